// Round 2
// baseline (7058.815 us; speedup 1.0000x reference)
//
#include <hip/hip_runtime.h>

#define N_NODES 100000
#define N_EDGES 600000
#define N_GRAPHS 1024
#define F_IN 32
#define GHC 128
#define NHID 512
#define NOUT 256
#define N_LAYERS 5
#define BN_EPS 1e-5f

// ---------------- GEMM: C[M,N] = act(A[M,K] (+A2) @ W[K,N] + bias) ----------------
#define BM 128
#define BN 64
#define BK 16
#define TM 8
#define TN 4

template<bool RELU, bool ADD2>
__global__ __launch_bounds__(256)
void gemm_kernel(const float* __restrict__ A, const float* __restrict__ A2,
                 const float* __restrict__ W, const float* __restrict__ bias,
                 float* __restrict__ C, int M, int K, int N)
{
    __shared__ float As[BK][BM + 4];
    __shared__ float Bs[BK][BN];
    const int tid = threadIdx.x;
    const int row0 = blockIdx.x * BM;
    const int col0 = blockIdx.y * BN;
    const int tx = tid & 15;        // n-tile position
    const int ty = tid >> 4;        // m-tile position
    const int lm = tid >> 1;        // A-load row (0..127)
    const int lk = (tid & 1) * 8;   // A-load k offset
    const int bkr = tid >> 4;       // B-load k row (0..15)
    const int bnc = (tid & 15) * 4; // B-load col offset

    float acc[TM][TN];
#pragma unroll
    for (int i = 0; i < TM; ++i)
#pragma unroll
        for (int j = 0; j < TN; ++j) acc[i][j] = 0.f;

    const int arow = row0 + lm;
    for (int k0 = 0; k0 < K; k0 += BK) {
        if (arow < M) {
            const float* ap = A + (size_t)arow * K + k0 + lk;
            float4 v0 = *(const float4*)ap;
            float4 v1 = *(const float4*)(ap + 4);
            if (ADD2) {
                const float* ap2 = A2 + (size_t)arow * K + k0 + lk;
                float4 w0 = *(const float4*)ap2;
                float4 w1 = *(const float4*)(ap2 + 4);
                v0.x += w0.x; v0.y += w0.y; v0.z += w0.z; v0.w += w0.w;
                v1.x += w1.x; v1.y += w1.y; v1.z += w1.z; v1.w += w1.w;
            }
            As[lk + 0][lm] = v0.x; As[lk + 1][lm] = v0.y;
            As[lk + 2][lm] = v0.z; As[lk + 3][lm] = v0.w;
            As[lk + 4][lm] = v1.x; As[lk + 5][lm] = v1.y;
            As[lk + 6][lm] = v1.z; As[lk + 7][lm] = v1.w;
        } else {
#pragma unroll
            for (int j = 0; j < 8; ++j) As[lk + j][lm] = 0.f;
        }
        {
            const float* wp = W + (size_t)(k0 + bkr) * N + col0 + bnc;
            *(float4*)&Bs[bkr][bnc] = *(const float4*)wp;
        }
        __syncthreads();
#pragma unroll
        for (int kk = 0; kk < BK; ++kk) {
            float a[TM], b[TN];
            *(float4*)&a[0] = *(const float4*)&As[kk][ty * TM];
            *(float4*)&a[4] = *(const float4*)&As[kk][ty * TM + 4];
            *(float4*)&b[0] = *(const float4*)&Bs[kk][tx * TN];
#pragma unroll
            for (int i = 0; i < TM; ++i)
#pragma unroll
                for (int j = 0; j < TN; ++j)
                    acc[i][j] = fmaf(a[i], b[j], acc[i][j]);
        }
        __syncthreads();
    }
    float4 bv = *(const float4*)(bias + col0 + tx * TN);
#pragma unroll
    for (int i = 0; i < TM; ++i) {
        int r = row0 + ty * TM + i;
        if (r < M) {
            float4 o;
            o.x = acc[i][0] + bv.x; o.y = acc[i][1] + bv.y;
            o.z = acc[i][2] + bv.z; o.w = acc[i][3] + bv.w;
            if (RELU) {
                o.x = fmaxf(o.x, 0.f); o.y = fmaxf(o.y, 0.f);
                o.z = fmaxf(o.z, 0.f); o.w = fmaxf(o.w, 0.f);
            }
            *(float4*)(C + (size_t)r * N + col0 + tx * TN) = o;
        }
    }
}

// ---------------- edge scatter-add: agg[dst] += x[src] ----------------
__global__ void scatter_add_kernel(const float* __restrict__ x,
    const int* __restrict__ src, const int* __restrict__ dst,
    float* __restrict__ agg, int logF4)
{
    int idx = blockIdx.x * blockDim.x + threadIdx.x;
    int e = idx >> logF4;
    if (e >= N_EDGES) return;
    int F4 = 1 << logF4;
    int f = (idx & (F4 - 1)) * 4;
    int F = F4 * 4;
    int s = src[e], d = dst[e];
    float4 v = *(const float4*)(x + (size_t)s * F + f);
    float* o = agg + (size_t)d * F + f;
    atomicAdd(o + 0, v.x); atomicAdd(o + 1, v.y);
    atomicAdd(o + 2, v.z); atomicAdd(o + 3, v.w);
}

// ---------------- per-graph node counts ----------------
__global__ void count_kernel(const int* __restrict__ batch, float* __restrict__ cnt)
{
    int i = blockIdx.x * blockDim.x + threadIdx.x;
    if (i < N_NODES) atomicAdd(&cnt[batch[i]], 1.f);
}

// ---------------- BN stats: per-channel sum and sumsq ----------------
__global__ __launch_bounds__(256)
void bn_stats_kernel(const float* __restrict__ h, float* __restrict__ sums)
{
    const int f = threadIdx.x & 127;
    const int rg = threadIdx.x >> 7;
    float s = 0.f, q = 0.f;
    for (int r = blockIdx.x * 2 + rg; r < N_NODES; r += gridDim.x * 2) {
        float v = h[(size_t)r * GHC + f];
        s += v; q += v * v;
    }
    __shared__ float ls[256], lq[256];
    ls[threadIdx.x] = s; lq[threadIdx.x] = q;
    __syncthreads();
    if (rg == 0) {
        s += ls[128 + f]; q += lq[128 + f];
        atomicAdd(&sums[f], s);
        atomicAdd(&sums[GHC + f], q);
    }
}

__global__ void bn_finalize_kernel(const float* __restrict__ sums,
    const float* __restrict__ gamma, const float* __restrict__ beta,
    float* __restrict__ ss)
{
    int f = threadIdx.x;
    if (f < GHC) {
        float mu = sums[f] * (1.f / N_NODES);
        float var = sums[GHC + f] * (1.f / N_NODES) - mu * mu;
        float sc = gamma[f] * rsqrtf(var + BN_EPS);
        ss[f] = sc;
        ss[GHC + f] = beta[f] - mu * sc;
    }
}

// ---------------- BN apply + relu + mean-pool scatter ----------------
__global__ __launch_bounds__(256)
void bn_apply_pool_kernel(const float* __restrict__ h2, const float* __restrict__ ss,
    const int* __restrict__ batch, float* __restrict__ hout,
    float* __restrict__ z, int loff)
{
    int idx = blockIdx.x * blockDim.x + threadIdx.x;
    int node = idx >> 5;
    if (node >= N_NODES) return;
    int f = (idx & 31) * 4;
    float4 v = *(const float4*)(h2 + (size_t)node * GHC + f);
    float4 sc = *(const float4*)(ss + f);
    float4 sh = *(const float4*)(ss + GHC + f);
    float4 o;
    o.x = fmaxf(v.x * sc.x + sh.x, 0.f);
    o.y = fmaxf(v.y * sc.y + sh.y, 0.f);
    o.z = fmaxf(v.z * sc.z + sh.z, 0.f);
    o.w = fmaxf(v.w * sc.w + sh.w, 0.f);
    *(float4*)(hout + (size_t)node * GHC + f) = o;
    int g = batch[node];
    float* zp = z + (size_t)g * (N_LAYERS * GHC) + loff + f;
    atomicAdd(zp + 0, o.x); atomicAdd(zp + 1, o.y);
    atomicAdd(zp + 2, o.z); atomicAdd(zp + 3, o.w);
}

// ---------------- divide pooled sums by counts ----------------
__global__ void scale_z_kernel(float* __restrict__ z, const float* __restrict__ cnt)
{
    int idx = blockIdx.x * blockDim.x + threadIdx.x;
    if (idx >= N_GRAPHS * N_LAYERS * GHC) return;
    int g = idx / (N_LAYERS * GHC);
    z[idx] *= 1.f / fmaxf(cnt[g], 1.f);
}

extern "C" void kernel_launch(void* const* d_in, const int* in_sizes, int n_in,
                              void* d_out, int out_size, void* d_ws, size_t ws_size,
                              hipStream_t stream)
{
    const float* x = (const float*)d_in[0];
    const int* edge = (const int*)d_in[1];
    const int* batch = (const int*)d_in[2];
    const float* W1_0 = (const float*)d_in[3];
    const float* b1_0 = (const float*)d_in[4];
    const float* W2_0 = (const float*)d_in[5];
    const float* b2_0 = (const float*)d_in[6];
    const float* W1s = (const float*)d_in[7];
    const float* b1s = (const float*)d_in[8];
    const float* W2s = (const float*)d_in[9];
    const float* b2s = (const float*)d_in[10];
    const float* gamma = (const float*)d_in[11];
    const float* beta = (const float*)d_in[12];
    const float* Wm1 = (const float*)d_in[13];
    const float* bm1 = (const float*)d_in[14];
    const float* Wm2 = (const float*)d_in[15];
    const float* bm2 = (const float*)d_in[16];
    const int* srcI = edge;
    const int* dstI = edge + N_EDGES;

    // workspace layout (floats) — total ~52.4M floats ~210 MB
    float* agg    = (float*)d_ws;                           // N*128 (doubles as h2)
    float* hidden = agg + (size_t)N_NODES * GHC;            // N*256
    float* hbuf   = hidden + (size_t)N_NODES * 2 * GHC;     // N*128 (layer io; safe to overwrite in-place at bn_apply)
    float* z      = hbuf + (size_t)N_NODES * GHC;           // 1024*640
    float* zh     = z + (size_t)N_GRAPHS * N_LAYERS * GHC;  // 1024*512
    float* cnt    = zh + (size_t)N_GRAPHS * NHID;           // 1024
    float* bnsums = cnt + N_GRAPHS;                         // 256
    float* bnss   = bnsums + 2 * GHC;                       // 256

    hipMemsetAsync(z, 0, sizeof(float) * (size_t)N_GRAPHS * N_LAYERS * GHC, stream);
    hipMemsetAsync(cnt, 0, sizeof(float) * N_GRAPHS, stream);
    count_kernel<<<(N_NODES + 255) / 256, 256, 0, stream>>>(batch, cnt);

    const float* hin = x;
    for (int l = 0; l < N_LAYERS; ++l) {
        const int F = (l == 0) ? F_IN : GHC;
        const int logF4 = (l == 0) ? 3 : 5;
        hipMemsetAsync(agg, 0, sizeof(float) * (size_t)N_NODES * F, stream);
        long long tot = (long long)N_EDGES << logF4;
        scatter_add_kernel<<<(int)((tot + 255) / 256), 256, 0, stream>>>(hin, srcI, dstI, agg, logF4);

        const float* W1 = (l == 0) ? W1_0 : W1s + (size_t)(l - 1) * GHC * 2 * GHC;
        const float* b1 = (l == 0) ? b1_0 : b1s + (size_t)(l - 1) * 2 * GHC;
        const float* W2 = (l == 0) ? W2_0 : W2s + (size_t)(l - 1) * 2 * GHC * GHC;
        const float* b2 = (l == 0) ? b2_0 : b2s + (size_t)(l - 1) * GHC;

        dim3 g1((N_NODES + BM - 1) / BM, (2 * GHC) / BN);
        gemm_kernel<true, true><<<g1, 256, 0, stream>>>(hin, agg, W1, b1, hidden, N_NODES, F, 2 * GHC);
        dim3 g2((N_NODES + BM - 1) / BM, GHC / BN);
        gemm_kernel<false, false><<<g2, 256, 0, stream>>>(hidden, nullptr, W2, b2, agg, N_NODES, 2 * GHC, GHC);

        hipMemsetAsync(bnsums, 0, sizeof(float) * 2 * GHC, stream);
        bn_stats_kernel<<<512, 256, 0, stream>>>(agg, bnsums);
        bn_finalize_kernel<<<1, GHC, 0, stream>>>(bnsums, gamma + l * GHC, beta + l * GHC, bnss);
        // bn_apply reads only agg/ss/batch -> writing hbuf in-place over hin is safe
        bn_apply_pool_kernel<<<(N_NODES * 32 + 255) / 256, 256, 0, stream>>>(agg, bnss, batch, hbuf, z, l * GHC);

        hin = hbuf;
    }

    scale_z_kernel<<<(N_GRAPHS * N_LAYERS * GHC + 255) / 256, 256, 0, stream>>>(z, cnt);
    dim3 gh1((N_GRAPHS + BM - 1) / BM, NHID / BN);
    gemm_kernel<true, false><<<gh1, 256, 0, stream>>>(z, nullptr, Wm1, bm1, zh, N_GRAPHS, N_LAYERS * GHC, NHID);
    dim3 gh2((N_GRAPHS + BM - 1) / BM, NOUT / BN);
    gemm_kernel<false, false><<<gh2, 256, 0, stream>>>(zh, nullptr, Wm2, bm2, (float*)d_out, N_GRAPHS, NHID, NOUT);
}

// Round 4
// 1852.360 us; speedup vs baseline: 3.8107x; 3.8107x over previous
//
#include <hip/hip_runtime.h>

#define N_NODES 100000
#define N_EDGES 600000
#define N_GRAPHS 1024
#define F_IN 32
#define GHC 128
#define NHID 512
#define NOUT 256
#define N_LAYERS 5
#define BN_EPS 1e-5f

// ==================== CSR build ====================
__global__ void deg_kernel(const int* __restrict__ dst, int* __restrict__ deg) {
    int e = blockIdx.x * blockDim.x + threadIdx.x;
    if (e < N_EDGES) atomicAdd(&deg[dst[e]], 1);
}

#define SCHUNK 1024
#define NCHUNKS ((N_NODES + SCHUNK - 1) / SCHUNK)   // 98

__global__ __launch_bounds__(1024)
void scan1_kernel(const int* __restrict__ deg, int* __restrict__ ptr, int* __restrict__ btot) {
    __shared__ int buf[SCHUNK];
    int t = threadIdx.x;
    int i = blockIdx.x * SCHUNK + t;
    int v = (i < N_NODES) ? deg[i] : 0;
    buf[t] = v;
    __syncthreads();
    for (int off = 1; off < SCHUNK; off <<= 1) {
        int u = (t >= off) ? buf[t - off] : 0;
        __syncthreads();
        buf[t] += u;
        __syncthreads();
    }
    if (i < N_NODES) ptr[i + 1] = buf[t];
    if (t == SCHUNK - 1) btot[blockIdx.x] = buf[t];
}

__global__ __launch_bounds__(128)
void scan2_kernel(int* __restrict__ btot) {
    __shared__ int buf[128];
    int t = threadIdx.x;
    int v = (t < NCHUNKS) ? btot[t] : 0;
    buf[t] = v;
    __syncthreads();
    for (int off = 1; off < 128; off <<= 1) {
        int u = (t >= off) ? buf[t - off] : 0;
        __syncthreads();
        buf[t] += u;
        __syncthreads();
    }
    if (t < NCHUNKS) btot[t] = buf[t] - v;   // exclusive scan of chunk totals
}

__global__ void scan3_kernel(int* __restrict__ ptr, const int* __restrict__ btot) {
    int i = blockIdx.x * blockDim.x + threadIdx.x;
    if (i < N_NODES) ptr[i + 1] += btot[i >> 10];
    if (i == 0) ptr[0] = 0;
}

__global__ void fill_kernel(const int* __restrict__ src, const int* __restrict__ dst,
                            int* __restrict__ cur, int* __restrict__ adj) {
    int e = blockIdx.x * blockDim.x + threadIdx.x;
    if (e >= N_EDGES) return;
    int p = atomicAdd(&cur[dst[e]], 1);
    adj[p] = src[e];
}

// graph_ptr[g] = lower_bound(batch, g)  (batch is sorted)
__global__ void gptr_kernel(const int* __restrict__ batch, int* __restrict__ gptr) {
    int g = blockIdx.x * blockDim.x + threadIdx.x;
    if (g > N_GRAPHS) return;
    int lo = 0, hi = N_NODES;
    while (lo < hi) { int mid = (lo + hi) >> 1; if (batch[mid] < g) lo = mid + 1; else hi = mid; }
    gptr[g] = lo;
}

// ==================== gather aggregation: agg[n] = x[n] + sum_{s in adj(n)} x[s] ====================
template<int F>
__global__ __launch_bounds__(256)
void gather_agg_kernel(const float* __restrict__ x, const int* __restrict__ ptr,
                       const int* __restrict__ adj, float* __restrict__ agg) {
    constexpr int F4 = F / 4;
    constexpr int NPB = 256 / F4;
    int f4 = threadIdx.x % F4;
    int n = blockIdx.x * NPB + threadIdx.x / F4;
    if (n >= N_NODES) return;
    const int fo = f4 * 4;
    float4 acc = *(const float4*)(x + (size_t)n * F + fo);
    int p1 = ptr[n + 1];
    for (int p = ptr[n]; p < p1; ++p) {
        int s = adj[p];
        float4 v = *(const float4*)(x + (size_t)s * F + fo);
        acc.x += v.x; acc.y += v.y; acc.z += v.z; acc.w += v.w;
    }
    *(float4*)(agg + (size_t)n * F + fo) = acc;
}

// ==================== GEMM 128x128 tile, 8x8 microtile (2x2 of 4-wide) ====================
template<bool RELU>
__global__ __launch_bounds__(256)
void gemm128_kernel(const float* __restrict__ A, const float* __restrict__ W,
                    const float* __restrict__ bias, float* __restrict__ C,
                    int M, int K, int N) {
    __shared__ float As[16][132];
    __shared__ float Bs[16][128];
    const int tid = threadIdx.x;
    const int row0 = blockIdx.x * 128;
    const int col0 = blockIdx.y * 128;
    const int tx = tid & 15;
    const int ty = tid >> 4;
    const int lm = tid >> 1;
    const int lk = (tid & 1) * 8;
    const int bkr = tid >> 4;
    const int bnc = (tid & 15) * 4;

    float acc[8][8];
#pragma unroll
    for (int i = 0; i < 8; ++i)
#pragma unroll
        for (int j = 0; j < 8; ++j) acc[i][j] = 0.f;

    const int arow = row0 + lm;
    for (int k0 = 0; k0 < K; k0 += 16) {
        if (arow < M) {
            const float* ap = A + (size_t)arow * K + k0 + lk;
            float4 v0 = *(const float4*)ap;
            float4 v1 = *(const float4*)(ap + 4);
            As[lk + 0][lm] = v0.x; As[lk + 1][lm] = v0.y;
            As[lk + 2][lm] = v0.z; As[lk + 3][lm] = v0.w;
            As[lk + 4][lm] = v1.x; As[lk + 5][lm] = v1.y;
            As[lk + 6][lm] = v1.z; As[lk + 7][lm] = v1.w;
        } else {
#pragma unroll
            for (int j = 0; j < 8; ++j) As[lk + j][lm] = 0.f;
        }
        const float* wp = W + (size_t)(k0 + bkr) * N + col0 + bnc;
        *(float4*)&Bs[bkr][bnc]      = *(const float4*)wp;
        *(float4*)&Bs[bkr][bnc + 64] = *(const float4*)(wp + 64);
        __syncthreads();
#pragma unroll
        for (int kk = 0; kk < 16; ++kk) {
            float a[8], b[8];
            *(float4*)&a[0] = *(const float4*)&As[kk][ty * 4];
            *(float4*)&a[4] = *(const float4*)&As[kk][ty * 4 + 64];
            *(float4*)&b[0] = *(const float4*)&Bs[kk][tx * 4];
            *(float4*)&b[4] = *(const float4*)&Bs[kk][tx * 4 + 64];
#pragma unroll
            for (int i = 0; i < 8; ++i)
#pragma unroll
                for (int j = 0; j < 8; ++j)
                    acc[i][j] = fmaf(a[i], b[j], acc[i][j]);
        }
        __syncthreads();
    }
    float4 bv0 = *(const float4*)(bias + col0 + tx * 4);
    float4 bv1 = *(const float4*)(bias + col0 + tx * 4 + 64);
    float bb[8] = {bv0.x, bv0.y, bv0.z, bv0.w, bv1.x, bv1.y, bv1.z, bv1.w};
#pragma unroll
    for (int i = 0; i < 8; ++i) {
        int r = row0 + ty * 4 + (i & 3) + (i >> 2) * 64;
        if (r < M) {
            float o[8];
#pragma unroll
            for (int j = 0; j < 8; ++j) {
                float t = acc[i][j] + bb[j];
                o[j] = RELU ? fmaxf(t, 0.f) : t;
            }
            *(float4*)(C + (size_t)r * N + col0 + tx * 4)      = *(float4*)&o[0];
            *(float4*)(C + (size_t)r * N + col0 + tx * 4 + 64) = *(float4*)&o[4];
        }
    }
}

// ==================== GEMM 64x64 tile, 4x4 microtile (head) ====================
template<bool RELU>
__global__ __launch_bounds__(256)
void gemm64_kernel(const float* __restrict__ A, const float* __restrict__ W,
                   const float* __restrict__ bias, float* __restrict__ C,
                   int M, int K, int N) {
    __shared__ float As[16][68];
    __shared__ float Bs[16][64];
    const int tid = threadIdx.x;
    const int row0 = blockIdx.x * 64;
    const int col0 = blockIdx.y * 64;
    const int tx = tid & 15;
    const int ty = tid >> 4;
    const int lm = tid >> 2;          // 0..63
    const int lk = (tid & 3) * 4;     // 0,4,8,12
    const int bkr = tid >> 4;         // 0..15
    const int bnc = (tid & 15) * 4;

    float acc[4][4];
#pragma unroll
    for (int i = 0; i < 4; ++i)
#pragma unroll
        for (int j = 0; j < 4; ++j) acc[i][j] = 0.f;

    const int arow = row0 + lm;
    for (int k0 = 0; k0 < K; k0 += 16) {
        if (arow < M) {
            float4 v = *(const float4*)(A + (size_t)arow * K + k0 + lk);
            As[lk + 0][lm] = v.x; As[lk + 1][lm] = v.y;
            As[lk + 2][lm] = v.z; As[lk + 3][lm] = v.w;
        } else {
#pragma unroll
            for (int j = 0; j < 4; ++j) As[lk + j][lm] = 0.f;
        }
        *(float4*)&Bs[bkr][bnc] = *(const float4*)(W + (size_t)(k0 + bkr) * N + col0 + bnc);
        __syncthreads();
#pragma unroll
        for (int kk = 0; kk < 16; ++kk) {
            float a[4], b[4];
            *(float4*)&a[0] = *(const float4*)&As[kk][ty * 4];
            *(float4*)&b[0] = *(const float4*)&Bs[kk][tx * 4];
#pragma unroll
            for (int i = 0; i < 4; ++i)
#pragma unroll
                for (int j = 0; j < 4; ++j)
                    acc[i][j] = fmaf(a[i], b[j], acc[i][j]);
        }
        __syncthreads();
    }
    float4 bv = *(const float4*)(bias + col0 + tx * 4);
    float bb[4] = {bv.x, bv.y, bv.z, bv.w};
#pragma unroll
    for (int i = 0; i < 4; ++i) {
        int r = row0 + ty * 4 + i;
        if (r < M) {
            float o[4];
#pragma unroll
            for (int j = 0; j < 4; ++j) {
                float t = acc[i][j] + bb[j];
                o[j] = RELU ? fmaxf(t, 0.f) : t;
            }
            *(float4*)(C + (size_t)r * N + col0 + tx * 4) = *(float4*)&o[0];
        }
    }
}

// ==================== BN ====================
__global__ __launch_bounds__(256)
void bn_stats_kernel(const float* __restrict__ h, float* __restrict__ sums) {
    const int f = threadIdx.x & 127;
    const int rg = threadIdx.x >> 7;
    float s = 0.f, q = 0.f;
    for (int r = blockIdx.x * 2 + rg; r < N_NODES; r += gridDim.x * 2) {
        float v = h[(size_t)r * GHC + f];
        s += v; q += v * v;
    }
    __shared__ float ls[256], lq[256];
    ls[threadIdx.x] = s; lq[threadIdx.x] = q;
    __syncthreads();
    if (rg == 0) {
        s += ls[128 + f]; q += lq[128 + f];
        atomicAdd(&sums[f], s);
        atomicAdd(&sums[GHC + f], q);
    }
}

__global__ void bn_finalize_kernel(const float* __restrict__ sums,
    const float* __restrict__ gamma, const float* __restrict__ beta,
    float* __restrict__ ss) {
    int f = threadIdx.x;
    if (f < GHC) {
        float mu = sums[f] * (1.f / N_NODES);
        float var = sums[GHC + f] * (1.f / N_NODES) - mu * mu;
        float sc = gamma[f] * rsqrtf(var + BN_EPS);
        ss[f] = sc;
        ss[GHC + f] = beta[f] - mu * sc;
    }
}

__global__ __launch_bounds__(256)
void bn_apply_kernel(const float* __restrict__ h2, const float* __restrict__ ss,
                     float* __restrict__ hout) {
    int idx = blockIdx.x * blockDim.x + threadIdx.x;
    int node = idx >> 5;
    if (node >= N_NODES) return;
    int f = (idx & 31) * 4;
    float4 v = *(const float4*)(h2 + (size_t)node * GHC + f);
    float4 sc = *(const float4*)(ss + f);
    float4 sh = *(const float4*)(ss + GHC + f);
    float4 o;
    o.x = fmaxf(v.x * sc.x + sh.x, 0.f);
    o.y = fmaxf(v.y * sc.y + sh.y, 0.f);
    o.z = fmaxf(v.z * sc.z + sh.z, 0.f);
    o.w = fmaxf(v.w * sc.w + sh.w, 0.f);
    *(float4*)(hout + (size_t)node * GHC + f) = o;
}

// ==================== per-graph mean pool (batch sorted, no atomics) ====================
__global__ __launch_bounds__(128)
void pool_kernel(const float* __restrict__ h, const int* __restrict__ gptr,
                 float* __restrict__ z, int loff) {
    int g = blockIdx.x;
    int f = threadIdx.x;
    int s = gptr[g], e = gptr[g + 1];
    float acc = 0.f;
    for (int i = s; i < e; ++i) acc += h[(size_t)i * GHC + f];
    z[(size_t)g * (N_LAYERS * GHC) + loff + f] = acc / fmaxf((float)(e - s), 1.f);
}

extern "C" void kernel_launch(void* const* d_in, const int* in_sizes, int n_in,
                              void* d_out, int out_size, void* d_ws, size_t ws_size,
                              hipStream_t stream)
{
    const float* x = (const float*)d_in[0];
    const int* edge = (const int*)d_in[1];
    const int* batch = (const int*)d_in[2];
    const float* W1_0 = (const float*)d_in[3];
    const float* b1_0 = (const float*)d_in[4];
    const float* W2_0 = (const float*)d_in[5];
    const float* b2_0 = (const float*)d_in[6];
    const float* W1s = (const float*)d_in[7];
    const float* b1s = (const float*)d_in[8];
    const float* W2s = (const float*)d_in[9];
    const float* b2s = (const float*)d_in[10];
    const float* gamma = (const float*)d_in[11];
    const float* beta = (const float*)d_in[12];
    const float* Wm1 = (const float*)d_in[13];
    const float* bm1 = (const float*)d_in[14];
    const float* Wm2 = (const float*)d_in[15];
    const float* bm2 = (const float*)d_in[16];
    const int* srcI = edge;
    const int* dstI = edge + N_EDGES;

    // ---- workspace layout ----
    float* agg    = (float*)d_ws;                           // N*128
    float* hidden = agg + (size_t)N_NODES * GHC;            // N*256
    float* hbuf   = hidden + (size_t)N_NODES * 2 * GHC;     // N*128
    float* z      = hbuf + (size_t)N_NODES * GHC;           // 1024*640
    float* zh     = z + (size_t)N_GRAPHS * N_LAYERS * GHC;  // 1024*512
    float* bnsums = zh + (size_t)N_GRAPHS * NHID;           // 256
    float* bnss   = bnsums + 2 * GHC;                       // 256
    int* ideg  = (int*)(bnss + 2 * GHC);                    // N (deg, then cur)
    int* iptr  = ideg + N_NODES;                            // N+1
    int* iadj  = iptr + N_NODES + 1;                        // E
    int* ibtot = iadj + N_EDGES;                            // 128
    int* igptr = ibtot + 128;                               // G+1

    // ---- CSR + graph ptr build (same work every call) ----
    hipMemsetAsync(ideg, 0, N_NODES * sizeof(int), stream);
    deg_kernel<<<(N_EDGES + 255) / 256, 256, 0, stream>>>(dstI, ideg);
    scan1_kernel<<<NCHUNKS, SCHUNK, 0, stream>>>(ideg, iptr, ibtot);
    scan2_kernel<<<1, 128, 0, stream>>>(ibtot);
    scan3_kernel<<<(N_NODES + 255) / 256, 256, 0, stream>>>(iptr, ibtot);
    hipMemcpyAsync(ideg, iptr, N_NODES * sizeof(int), hipMemcpyDeviceToDevice, stream);
    fill_kernel<<<(N_EDGES + 255) / 256, 256, 0, stream>>>(srcI, dstI, ideg, iadj);
    gptr_kernel<<<(N_GRAPHS + 1 + 255) / 256, 256, 0, stream>>>(batch, igptr);

    const float* hin = x;
    for (int l = 0; l < N_LAYERS; ++l) {
        const int F = (l == 0) ? F_IN : GHC;
        if (l == 0)
            gather_agg_kernel<F_IN><<<(N_NODES + 31) / 32, 256, 0, stream>>>(hin, iptr, iadj, agg);
        else
            gather_agg_kernel<GHC><<<(N_NODES + 7) / 8, 256, 0, stream>>>(hin, iptr, iadj, agg);

        const float* W1 = (l == 0) ? W1_0 : W1s + (size_t)(l - 1) * GHC * 2 * GHC;
        const float* b1 = (l == 0) ? b1_0 : b1s + (size_t)(l - 1) * 2 * GHC;
        const float* W2 = (l == 0) ? W2_0 : W2s + (size_t)(l - 1) * 2 * GHC * GHC;
        const float* b2 = (l == 0) ? b2_0 : b2s + (size_t)(l - 1) * GHC;

        dim3 g1((N_NODES + 127) / 128, (2 * GHC) / 128);
        gemm128_kernel<true><<<g1, 256, 0, stream>>>(agg, W1, b1, hidden, N_NODES, F, 2 * GHC);
        dim3 g2((N_NODES + 127) / 128, GHC / 128);
        gemm128_kernel<false><<<g2, 256, 0, stream>>>(hidden, W2, b2, agg, N_NODES, 2 * GHC, GHC);

        hipMemsetAsync(bnsums, 0, sizeof(float) * 2 * GHC, stream);
        bn_stats_kernel<<<512, 256, 0, stream>>>(agg, bnsums);
        bn_finalize_kernel<<<1, GHC, 0, stream>>>(bnsums, gamma + l * GHC, beta + l * GHC, bnss);
        bn_apply_kernel<<<(N_NODES * 32 + 255) / 256, 256, 0, stream>>>(agg, bnss, hbuf);
        pool_kernel<<<N_GRAPHS, 128, 0, stream>>>(hbuf, igptr, z, l * GHC);

        hin = hbuf;
    }

    dim3 gh1(N_GRAPHS / 64, NHID / 64);
    gemm64_kernel<true><<<gh1, 256, 0, stream>>>(z, Wm1, bm1, zh, N_GRAPHS, N_LAYERS * GHC, NHID);
    dim3 gh2(N_GRAPHS / 64, NOUT / 64);
    gemm64_kernel<false><<<gh2, 256, 0, stream>>>(zh, Wm2, bm2, (float*)d_out, N_GRAPHS, NHID, NOUT);
}

// Round 5
// 1584.111 us; speedup vs baseline: 4.4560x; 1.1693x over previous
//
#include <hip/hip_runtime.h>

#define N_NODES 100000
#define N_EDGES 600000
#define N_GRAPHS 1024
#define F_IN 32
#define GHC 128
#define NHID 512
#define NOUT 256
#define N_LAYERS 5
#define BN_EPS 1e-5f

typedef __attribute__((ext_vector_type(4))) float f32x4;
typedef __attribute__((ext_vector_type(8))) short bf16x8;

__device__ __forceinline__ unsigned short f2bf(float f) {
    unsigned int u = __float_as_uint(f);
    u = u + 0x7fffu + ((u >> 16) & 1u);
    return (unsigned short)(u >> 16);
}
__device__ __forceinline__ float bf2f(unsigned short h) {
    return __uint_as_float(((unsigned int)h) << 16);
}
__device__ __forceinline__ void load_lds16(const void* g, void* l) {
    __builtin_amdgcn_global_load_lds((const __attribute__((address_space(1))) void*)g,
                                     (__attribute__((address_space(3))) void*)l, 16, 0, 0);
}

// ==================== CSR build ====================
__global__ void deg_kernel(const int* __restrict__ dst, int* __restrict__ deg) {
    int e = blockIdx.x * blockDim.x + threadIdx.x;
    if (e < N_EDGES) atomicAdd(&deg[dst[e]], 1);
}

#define SCHUNK 1024
#define NCHUNKS ((N_NODES + SCHUNK - 1) / SCHUNK)   // 98

__global__ __launch_bounds__(1024)
void scan1_kernel(const int* __restrict__ deg, int* __restrict__ ptr, int* __restrict__ btot) {
    __shared__ int buf[SCHUNK];
    int t = threadIdx.x;
    int i = blockIdx.x * SCHUNK + t;
    int v = (i < N_NODES) ? deg[i] : 0;
    buf[t] = v;
    __syncthreads();
    for (int off = 1; off < SCHUNK; off <<= 1) {
        int u = (t >= off) ? buf[t - off] : 0;
        __syncthreads();
        buf[t] += u;
        __syncthreads();
    }
    if (i < N_NODES) ptr[i + 1] = buf[t];
    if (t == SCHUNK - 1) btot[blockIdx.x] = buf[t];
}

__global__ __launch_bounds__(128)
void scan2_kernel(int* __restrict__ btot) {
    __shared__ int buf[128];
    int t = threadIdx.x;
    int v = (t < NCHUNKS) ? btot[t] : 0;
    buf[t] = v;
    __syncthreads();
    for (int off = 1; off < 128; off <<= 1) {
        int u = (t >= off) ? buf[t - off] : 0;
        __syncthreads();
        buf[t] += u;
        __syncthreads();
    }
    if (t < NCHUNKS) btot[t] = buf[t] - v;
}

__global__ void scan3_kernel(int* __restrict__ ptr, const int* __restrict__ btot) {
    int i = blockIdx.x * blockDim.x + threadIdx.x;
    if (i < N_NODES) ptr[i + 1] += btot[i >> 10];
    if (i == 0) ptr[0] = 0;
}

__global__ void fill_kernel(const int* __restrict__ src, const int* __restrict__ dst,
                            int* __restrict__ cur, int* __restrict__ adj) {
    int e = blockIdx.x * blockDim.x + threadIdx.x;
    if (e >= N_EDGES) return;
    int p = atomicAdd(&cur[dst[e]], 1);
    adj[p] = src[e];
}

__global__ void gptr_kernel(const int* __restrict__ batch, int* __restrict__ gptr) {
    int g = blockIdx.x * blockDim.x + threadIdx.x;
    if (g > N_GRAPHS) return;
    int lo = 0, hi = N_NODES;
    while (lo < hi) { int mid = (lo + hi) >> 1; if (batch[mid] < g) lo = mid + 1; else hi = mid; }
    gptr[g] = lo;
}

// ==================== weight transpose + bf16 split: W[K][N] -> Wt_hi/lo [N][K] ====================
__global__ void wconv_kernel(const float* __restrict__ W, unsigned short* __restrict__ thi,
                             unsigned short* __restrict__ tlo, int K, int N) {
    int i = blockIdx.x * blockDim.x + threadIdx.x;
    if (i >= K * N) return;
    int k = i / N, n = i - k * N;
    float v = W[i];
    unsigned short h = f2bf(v);
    thi[(size_t)n * K + k] = h;
    tlo[(size_t)n * K + k] = f2bf(v - bf2f(h));
}

// ==================== gather aggregation -> bf16 hi/lo planes ====================
template<int F>
__global__ __launch_bounds__(256)
void gather_agg_kernel(const float* __restrict__ x, const int* __restrict__ ptr,
                       const int* __restrict__ adj,
                       unsigned short* __restrict__ ahi, unsigned short* __restrict__ alo) {
    constexpr int F4 = F / 4;
    constexpr int NPB = 256 / F4;
    int f4 = threadIdx.x % F4;
    int n = blockIdx.x * NPB + threadIdx.x / F4;
    if (n >= N_NODES) return;
    const int fo = f4 * 4;
    float4 acc = *(const float4*)(x + (size_t)n * F + fo);
    int p1 = ptr[n + 1];
    for (int p = ptr[n]; p < p1; ++p) {
        int s = adj[p];
        float4 v = *(const float4*)(x + (size_t)s * F + fo);
        acc.x += v.x; acc.y += v.y; acc.z += v.z; acc.w += v.w;
    }
    ushort4 h4, l4;
    h4.x = f2bf(acc.x); l4.x = f2bf(acc.x - bf2f(h4.x));
    h4.y = f2bf(acc.y); l4.y = f2bf(acc.y - bf2f(h4.y));
    h4.z = f2bf(acc.z); l4.z = f2bf(acc.z - bf2f(h4.z));
    h4.w = f2bf(acc.w); l4.w = f2bf(acc.w - bf2f(h4.w));
    *(ushort4*)(ahi + (size_t)n * F + fo) = h4;
    *(ushort4*)(alo + (size_t)n * F + fo) = l4;
}

// ==================== split-bf16 MFMA GEMM ====================
// C[M,N] = A @ B + bias, A given as hi/lo bf16 planes [M][K], B as Bt hi/lo [N][K].
// 3-term split: A*B ~= Ahi*Bhi + Ahi*Blo + Alo*Bhi  (fp32-level accuracy).
// MODE 1: relu, write bf16 hi/lo planes. MODE 2: no relu, write fp32 + fused BN sum/sumsq.
template<int MODE>
__global__ __launch_bounds__(256)
void mfma_gemm(const unsigned short* __restrict__ Ahi, const unsigned short* __restrict__ Alo,
               const unsigned short* __restrict__ Bhi, const unsigned short* __restrict__ Blo,
               const float* __restrict__ bias,
               unsigned short* __restrict__ Ohi, unsigned short* __restrict__ Olo,
               float* __restrict__ Of, float* __restrict__ bnsums,
               int M, int K, int N)
{
    // k-group-major LDS: [plane][g][row][8] ; frag read = 16B contiguous per (g,row)
    __shared__ unsigned short As[2][4][128][8];
    __shared__ unsigned short Bs[2][4][128][8];
    __shared__ float sred[128], qred[128];

    const int tid = threadIdx.x;
    const int wv = tid >> 6, lane = tid & 63;
    const int r = lane & 15, g = lane >> 4;
    const int wm = wv >> 1, wn = wv & 1;
    const int row0 = blockIdx.x * 128, col0 = blockIdx.y * 128;

    if (MODE == 2 && tid < 128) { sred[tid] = 0.f; qred[tid] = 0.f; }

    f32x4 acc[4][4];
#pragma unroll
    for (int mi = 0; mi < 4; ++mi)
#pragma unroll
        for (int ni = 0; ni < 4; ++ni) acc[mi][ni] = 0.f;

    for (int k0 = 0; k0 < K; k0 += 32) {
        // stage 128x32 hi/lo tiles of A and Bt via global_load_lds (16B/lane)
#pragma unroll
        for (int pass = 0; pass < 2; ++pass) {
            const int c = pass * 256 + wv * 64 + lane;       // cell = g*128 + row
            const int grow = c & 127, gg = c >> 7;
            int arow = row0 + grow; arow = arow < M ? arow : M - 1;
            const size_t aoff = (size_t)arow * K + k0 + gg * 8;
            const size_t boff = (size_t)(col0 + grow) * K + k0 + gg * 8;
            unsigned short* ldsA = (unsigned short*)As + (size_t)(pass * 256 + wv * 64) * 8;
            unsigned short* ldsB = (unsigned short*)Bs + (size_t)(pass * 256 + wv * 64) * 8;
            load_lds16(Ahi + aoff, ldsA);
            load_lds16(Alo + aoff, ldsA + 4096);
            load_lds16(Bhi + boff, ldsB);
            load_lds16(Blo + boff, ldsB + 4096);
        }
        __syncthreads();

        bf16x8 ah[4], al[4], bh[4], bl[4];
#pragma unroll
        for (int i = 0; i < 4; ++i) {
            const int ar = wm * 64 + i * 16 + r;
            const int br = wn * 64 + i * 16 + r;
            ah[i] = *(const bf16x8*)&As[0][g][ar][0];
            al[i] = *(const bf16x8*)&As[1][g][ar][0];
            bh[i] = *(const bf16x8*)&Bs[0][g][br][0];
            bl[i] = *(const bf16x8*)&Bs[1][g][br][0];
        }
#pragma unroll
        for (int mi = 0; mi < 4; ++mi)
#pragma unroll
            for (int ni = 0; ni < 4; ++ni) {
                acc[mi][ni] = __builtin_amdgcn_mfma_f32_16x16x32_bf16(ah[mi], bh[ni], acc[mi][ni], 0, 0, 0);
                acc[mi][ni] = __builtin_amdgcn_mfma_f32_16x16x32_bf16(ah[mi], bl[ni], acc[mi][ni], 0, 0, 0);
                acc[mi][ni] = __builtin_amdgcn_mfma_f32_16x16x32_bf16(al[mi], bh[ni], acc[mi][ni], 0, 0, 0);
            }
        __syncthreads();
    }

    // epilogue: D row = row0 + wm*64 + mi*16 + g*4 + reg ; col = col0 + wn*64 + ni*16 + r
    if (MODE == 1) {
#pragma unroll
        for (int ni = 0; ni < 4; ++ni) {
            const int col = col0 + wn * 64 + ni * 16 + r;
            const float bb = bias[col];
#pragma unroll
            for (int mi = 0; mi < 4; ++mi)
#pragma unroll
                for (int reg = 0; reg < 4; ++reg) {
                    const int row = row0 + wm * 64 + mi * 16 + g * 4 + reg;
                    if (row < M) {
                        float v = fmaxf(acc[mi][ni][reg] + bb, 0.f);
                        unsigned short h = f2bf(v);
                        Ohi[(size_t)row * N + col] = h;
                        Olo[(size_t)row * N + col] = f2bf(v - bf2f(h));
                    }
                }
        }
    } else {
        float sl[4] = {0.f, 0.f, 0.f, 0.f}, ql[4] = {0.f, 0.f, 0.f, 0.f};
#pragma unroll
        for (int ni = 0; ni < 4; ++ni) {
            const int col = col0 + wn * 64 + ni * 16 + r;
            const float bb = bias[col];
#pragma unroll
            for (int mi = 0; mi < 4; ++mi)
#pragma unroll
                for (int reg = 0; reg < 4; ++reg) {
                    const int row = row0 + wm * 64 + mi * 16 + g * 4 + reg;
                    if (row < M) {
                        float v = acc[mi][ni][reg] + bb;
                        Of[(size_t)row * N + col] = v;
                        sl[ni] += v; ql[ni] += v * v;
                    }
                }
        }
#pragma unroll
        for (int ni = 0; ni < 4; ++ni) {
            atomicAdd(&sred[wn * 64 + ni * 16 + r], sl[ni]);
            atomicAdd(&qred[wn * 64 + ni * 16 + r], ql[ni]);
        }
        __syncthreads();
        if (tid < 128) {
            atomicAdd(&bnsums[tid], sred[tid]);
            atomicAdd(&bnsums[GHC + tid], qred[tid]);
        }
    }
}

// ==================== BN finalize / apply ====================
__global__ void bn_finalize_kernel(const float* __restrict__ sums,
    const float* __restrict__ gamma, const float* __restrict__ beta,
    float* __restrict__ ss) {
    int f = threadIdx.x;
    if (f < GHC) {
        float mu = sums[f] * (1.f / N_NODES);
        float var = sums[GHC + f] * (1.f / N_NODES) - mu * mu;
        float sc = gamma[f] * rsqrtf(var + BN_EPS);
        ss[f] = sc;
        ss[GHC + f] = beta[f] - mu * sc;
    }
}

__global__ __launch_bounds__(256)
void bn_apply_kernel(const float* __restrict__ h2, const float* __restrict__ ss,
                     float* __restrict__ hout) {
    int idx = blockIdx.x * blockDim.x + threadIdx.x;
    int node = idx >> 5;
    if (node >= N_NODES) return;
    int f = (idx & 31) * 4;
    float4 v = *(const float4*)(h2 + (size_t)node * GHC + f);
    float4 sc = *(const float4*)(ss + f);
    float4 sh = *(const float4*)(ss + GHC + f);
    float4 o;
    o.x = fmaxf(v.x * sc.x + sh.x, 0.f);
    o.y = fmaxf(v.y * sc.y + sh.y, 0.f);
    o.z = fmaxf(v.z * sc.z + sh.z, 0.f);
    o.w = fmaxf(v.w * sc.w + sh.w, 0.f);
    *(float4*)(hout + (size_t)node * GHC + f) = o;
}

// ==================== per-graph mean pool (batch sorted) ====================
__global__ __launch_bounds__(128)
void pool_kernel(const float* __restrict__ h, const int* __restrict__ gptr,
                 float* __restrict__ z, int loff) {
    int g = blockIdx.x;
    int f = threadIdx.x;
    int s = gptr[g], e = gptr[g + 1];
    float acc = 0.f;
    for (int i = s; i < e; ++i) acc += h[(size_t)i * GHC + f];
    z[(size_t)g * (N_LAYERS * GHC) + loff + f] = acc / fmaxf((float)(e - s), 1.f);
}

// ==================== fp32 GEMM 64x64 (head, tiny) ====================
template<bool RELU>
__global__ __launch_bounds__(256)
void gemm64_kernel(const float* __restrict__ A, const float* __restrict__ W,
                   const float* __restrict__ bias, float* __restrict__ C,
                   int M, int K, int N) {
    __shared__ float As[16][68];
    __shared__ float Bs[16][64];
    const int tid = threadIdx.x;
    const int row0 = blockIdx.x * 64;
    const int col0 = blockIdx.y * 64;
    const int tx = tid & 15;
    const int ty = tid >> 4;
    const int lm = tid >> 2;
    const int lk = (tid & 3) * 4;
    const int bkr = tid >> 4;
    const int bnc = (tid & 15) * 4;

    float acc[4][4];
#pragma unroll
    for (int i = 0; i < 4; ++i)
#pragma unroll
        for (int j = 0; j < 4; ++j) acc[i][j] = 0.f;

    const int arow = row0 + lm;
    for (int k0 = 0; k0 < K; k0 += 16) {
        if (arow < M) {
            float4 v = *(const float4*)(A + (size_t)arow * K + k0 + lk);
            As[lk + 0][lm] = v.x; As[lk + 1][lm] = v.y;
            As[lk + 2][lm] = v.z; As[lk + 3][lm] = v.w;
        } else {
#pragma unroll
            for (int j = 0; j < 4; ++j) As[lk + j][lm] = 0.f;
        }
        *(float4*)&Bs[bkr][bnc] = *(const float4*)(W + (size_t)(k0 + bkr) * N + col0 + bnc);
        __syncthreads();
#pragma unroll
        for (int kk = 0; kk < 16; ++kk) {
            float a[4], b[4];
            *(float4*)&a[0] = *(const float4*)&As[kk][ty * 4];
            *(float4*)&b[0] = *(const float4*)&Bs[kk][tx * 4];
#pragma unroll
            for (int i = 0; i < 4; ++i)
#pragma unroll
                for (int j = 0; j < 4; ++j)
                    acc[i][j] = fmaf(a[i], b[j], acc[i][j]);
        }
        __syncthreads();
    }
    float4 bv = *(const float4*)(bias + col0 + tx * 4);
    float bb[4] = {bv.x, bv.y, bv.z, bv.w};
#pragma unroll
    for (int i = 0; i < 4; ++i) {
        int row = row0 + ty * 4 + i;
        if (row < M) {
            float o[4];
#pragma unroll
            for (int j = 0; j < 4; ++j) {
                float t = acc[i][j] + bb[j];
                o[j] = RELU ? fmaxf(t, 0.f) : t;
            }
            *(float4*)(C + (size_t)row * N + col0 + tx * 4) = *(float4*)&o[0];
        }
    }
}

extern "C" void kernel_launch(void* const* d_in, const int* in_sizes, int n_in,
                              void* d_out, int out_size, void* d_ws, size_t ws_size,
                              hipStream_t stream)
{
    const float* x = (const float*)d_in[0];
    const int* edge = (const int*)d_in[1];
    const int* batch = (const int*)d_in[2];
    const float* W1_0 = (const float*)d_in[3];
    const float* b1_0 = (const float*)d_in[4];
    const float* W2_0 = (const float*)d_in[5];
    const float* b2_0 = (const float*)d_in[6];
    const float* W1s = (const float*)d_in[7];
    const float* b1s = (const float*)d_in[8];
    const float* W2s = (const float*)d_in[9];
    const float* b2s = (const float*)d_in[10];
    const float* gamma = (const float*)d_in[11];
    const float* beta = (const float*)d_in[12];
    const float* Wm1 = (const float*)d_in[13];
    const float* bm1 = (const float*)d_in[14];
    const float* Wm2 = (const float*)d_in[15];
    const float* bm2 = (const float*)d_in[16];
    const int* srcI = edge;
    const int* dstI = edge + N_EDGES;

    // ---- workspace layout (~213 MB) ----
    unsigned short* agg_hi = (unsigned short*)d_ws;              // N*128 bf16
    unsigned short* agg_lo = agg_hi + (size_t)N_NODES * GHC;     // N*128 bf16
    float* h2 = (float*)d_ws;                                    // N*128 fp32 (aliases agg planes; agg dead when written)
    unsigned short* hid_hi = agg_lo + (size_t)N_NODES * GHC;     // N*256 bf16
    unsigned short* hid_lo = hid_hi + (size_t)N_NODES * 2 * GHC; // N*256 bf16
    float* hbuf = (float*)(hid_lo + (size_t)N_NODES * 2 * GHC);  // N*128 fp32
    float* z = hbuf + (size_t)N_NODES * GHC;                     // 1024*640
    float* zh = z + (size_t)N_GRAPHS * N_LAYERS * GHC;           // 1024*512
    float* bnsums = zh + (size_t)N_GRAPHS * NHID;                // 256
    float* bnss = bnsums + 2 * GHC;                              // 256
    unsigned short* w1t_hi = (unsigned short*)(bnss + 2 * GHC);  // 256*128
    unsigned short* w1t_lo = w1t_hi + 256 * GHC;
    unsigned short* w2t_hi = w1t_lo + 256 * GHC;                 // 128*256
    unsigned short* w2t_lo = w2t_hi + 256 * GHC;
    int* ideg = (int*)(w2t_lo + 256 * GHC);                      // N
    int* iptr = ideg + N_NODES;                                  // N+1
    int* iadj = iptr + N_NODES + 1;                              // E
    int* ibtot = iadj + N_EDGES;                                 // 128
    int* igptr = ibtot + 128;                                    // G+1

    // ---- CSR + graph ptr build ----
    hipMemsetAsync(ideg, 0, N_NODES * sizeof(int), stream);
    deg_kernel<<<(N_EDGES + 255) / 256, 256, 0, stream>>>(dstI, ideg);
    scan1_kernel<<<NCHUNKS, SCHUNK, 0, stream>>>(ideg, iptr, ibtot);
    scan2_kernel<<<1, 128, 0, stream>>>(ibtot);
    scan3_kernel<<<(N_NODES + 255) / 256, 256, 0, stream>>>(iptr, ibtot);
    hipMemcpyAsync(ideg, iptr, N_NODES * sizeof(int), hipMemcpyDeviceToDevice, stream);
    fill_kernel<<<(N_EDGES + 255) / 256, 256, 0, stream>>>(srcI, dstI, ideg, iadj);
    gptr_kernel<<<(N_GRAPHS + 1 + 255) / 256, 256, 0, stream>>>(batch, igptr);

    const int MB = (N_NODES + 127) / 128;   // 782
    const float* hin = x;
    for (int l = 0; l < N_LAYERS; ++l) {
        const int F = (l == 0) ? F_IN : GHC;
        const float* W1 = (l == 0) ? W1_0 : W1s + (size_t)(l - 1) * GHC * 2 * GHC;
        const float* b1 = (l == 0) ? b1_0 : b1s + (size_t)(l - 1) * 2 * GHC;
        const float* W2 = (l == 0) ? W2_0 : W2s + (size_t)(l - 1) * 2 * GHC * GHC;
        const float* b2 = (l == 0) ? b2_0 : b2s + (size_t)(l - 1) * GHC;

        wconv_kernel<<<(F * 2 * GHC + 255) / 256, 256, 0, stream>>>(W1, w1t_hi, w1t_lo, F, 2 * GHC);
        wconv_kernel<<<(2 * GHC * GHC + 255) / 256, 256, 0, stream>>>(W2, w2t_hi, w2t_lo, 2 * GHC, GHC);

        if (l == 0)
            gather_agg_kernel<F_IN><<<(N_NODES + 31) / 32, 256, 0, stream>>>(hin, iptr, iadj, agg_hi, agg_lo);
        else
            gather_agg_kernel<GHC><<<(N_NODES + 7) / 8, 256, 0, stream>>>(hin, iptr, iadj, agg_hi, agg_lo);

        // GEMM1: [M,F] @ [F,256] -> hidden bf16 planes (relu fused)
        mfma_gemm<1><<<dim3(MB, 2), 256, 0, stream>>>(agg_hi, agg_lo, w1t_hi, w1t_lo, b1,
                                                      hid_hi, hid_lo, nullptr, nullptr,
                                                      N_NODES, F, 2 * GHC);
        // GEMM2: [M,256] @ [256,128] -> h2 fp32 (+ fused BN stats)
        hipMemsetAsync(bnsums, 0, sizeof(float) * 2 * GHC, stream);
        mfma_gemm<2><<<dim3(MB, 1), 256, 0, stream>>>(hid_hi, hid_lo, w2t_hi, w2t_lo, b2,
                                                      nullptr, nullptr, h2, bnsums,
                                                      N_NODES, 2 * GHC, GHC);

        bn_finalize_kernel<<<1, GHC, 0, stream>>>(bnsums, gamma + l * GHC, beta + l * GHC, bnss);
        bn_apply_kernel<<<(N_NODES * 32 + 255) / 256, 256, 0, stream>>>(h2, bnss, hbuf);
        pool_kernel<<<N_GRAPHS, 128, 0, stream>>>(hbuf, igptr, z, l * GHC);

        hin = hbuf;
    }

    dim3 gh1(N_GRAPHS / 64, NHID / 64);
    gemm64_kernel<true><<<gh1, 256, 0, stream>>>(z, Wm1, bm1, zh, N_GRAPHS, N_LAYERS * GHC, NHID);
    dim3 gh2(N_GRAPHS / 64, NOUT / 64);
    gemm64_kernel<false><<<gh2, 256, 0, stream>>>(zh, Wm2, bm2, (float*)d_out, N_GRAPHS, NHID, NOUT);
}

// Round 6
// 1475.823 us; speedup vs baseline: 4.7830x; 1.0734x over previous
//
#include <hip/hip_runtime.h>

#define N_NODES 100000
#define N_EDGES 600000
#define N_GRAPHS 1024
#define F_IN 32
#define GHC 128
#define NHID 512
#define NOUT 256
#define N_LAYERS 5
#define BN_EPS 1e-5f

typedef __attribute__((ext_vector_type(4))) float f32x4;
typedef __attribute__((ext_vector_type(8))) short bf16x8;

__device__ __forceinline__ unsigned short f2bf(float f) {
    unsigned int u = __float_as_uint(f);
    u = u + 0x7fffu + ((u >> 16) & 1u);
    return (unsigned short)(u >> 16);
}
__device__ __forceinline__ float bf2f(unsigned short h) {
    return __uint_as_float(((unsigned int)h) << 16);
}
__device__ __forceinline__ void load_lds16(const void* g, void* l) {
    __builtin_amdgcn_global_load_lds((const __attribute__((address_space(1))) void*)g,
                                     (__attribute__((address_space(3))) void*)l, 16, 0, 0);
}

// ==================== CSR build ====================
__global__ void deg_kernel(const int* __restrict__ dst, int* __restrict__ deg) {
    int e = blockIdx.x * blockDim.x + threadIdx.x;
    if (e < N_EDGES) atomicAdd(&deg[dst[e]], 1);
}

#define SCHUNK 1024
#define NCHUNKS ((N_NODES + SCHUNK - 1) / SCHUNK)   // 98

__global__ __launch_bounds__(1024)
void scan1_kernel(const int* __restrict__ deg, int* __restrict__ ptr, int* __restrict__ btot) {
    __shared__ int buf[SCHUNK];
    int t = threadIdx.x;
    int i = blockIdx.x * SCHUNK + t;
    int v = (i < N_NODES) ? deg[i] : 0;
    buf[t] = v;
    __syncthreads();
    for (int off = 1; off < SCHUNK; off <<= 1) {
        int u = (t >= off) ? buf[t - off] : 0;
        __syncthreads();
        buf[t] += u;
        __syncthreads();
    }
    if (i < N_NODES) ptr[i + 1] = buf[t];
    if (t == SCHUNK - 1) btot[blockIdx.x] = buf[t];
}

__global__ __launch_bounds__(128)
void scan2_kernel(int* __restrict__ btot) {
    __shared__ int buf[128];
    int t = threadIdx.x;
    int v = (t < NCHUNKS) ? btot[t] : 0;
    buf[t] = v;
    __syncthreads();
    for (int off = 1; off < 128; off <<= 1) {
        int u = (t >= off) ? buf[t - off] : 0;
        __syncthreads();
        buf[t] += u;
        __syncthreads();
    }
    if (t < NCHUNKS) btot[t] = buf[t] - v;
}

__global__ void scan3_kernel(int* __restrict__ ptr, const int* __restrict__ btot) {
    int i = blockIdx.x * blockDim.x + threadIdx.x;
    if (i < N_NODES) ptr[i + 1] += btot[i >> 10];
    if (i == 0) ptr[0] = 0;
}

__global__ void fill_kernel(const int* __restrict__ src, const int* __restrict__ dst,
                            int* __restrict__ cur, int* __restrict__ adj) {
    int e = blockIdx.x * blockDim.x + threadIdx.x;
    if (e >= N_EDGES) return;
    int p = atomicAdd(&cur[dst[e]], 1);
    adj[p] = src[e];
}

__global__ void gptr_kernel(const int* __restrict__ batch, int* __restrict__ gptr) {
    int g = blockIdx.x * blockDim.x + threadIdx.x;
    if (g > N_GRAPHS) return;
    int lo = 0, hi = N_NODES;
    while (lo < hi) { int mid = (lo + hi) >> 1; if (batch[mid] < g) lo = mid + 1; else hi = mid; }
    gptr[g] = lo;
}

// ==================== weight transpose + bf16 split: W[K][N] -> Wt_hi/lo [N][K] ====================
__global__ void wconv_kernel(const float* __restrict__ W, unsigned short* __restrict__ thi,
                             unsigned short* __restrict__ tlo, int K, int N) {
    int i = blockIdx.x * blockDim.x + threadIdx.x;
    if (i >= K * N) return;
    int k = i / N, n = i - k * N;
    float v = W[i];
    unsigned short h = f2bf(v);
    thi[(size_t)n * K + k] = h;
    tlo[(size_t)n * K + k] = f2bf(v - bf2f(h));
}

// ==================== gather aggregation -> bf16 hi/lo planes ====================
template<int F>
__global__ __launch_bounds__(256)
void gather_agg_kernel(const float* __restrict__ x, const int* __restrict__ ptr,
                       const int* __restrict__ adj,
                       unsigned short* __restrict__ ahi, unsigned short* __restrict__ alo) {
    constexpr int F4 = F / 4;
    constexpr int NPB = 256 / F4;
    int f4 = threadIdx.x % F4;
    int n = blockIdx.x * NPB + threadIdx.x / F4;
    if (n >= N_NODES) return;
    const int fo = f4 * 4;
    float4 acc = *(const float4*)(x + (size_t)n * F + fo);
    int p1 = ptr[n + 1];
    for (int p = ptr[n]; p < p1; ++p) {
        int s = adj[p];
        float4 v = *(const float4*)(x + (size_t)s * F + fo);
        acc.x += v.x; acc.y += v.y; acc.z += v.z; acc.w += v.w;
    }
    ushort4 h4, l4;
    h4.x = f2bf(acc.x); l4.x = f2bf(acc.x - bf2f(h4.x));
    h4.y = f2bf(acc.y); l4.y = f2bf(acc.y - bf2f(h4.y));
    h4.z = f2bf(acc.z); l4.z = f2bf(acc.z - bf2f(h4.z));
    h4.w = f2bf(acc.w); l4.w = f2bf(acc.w - bf2f(h4.w));
    *(ushort4*)(ahi + (size_t)n * F + fo) = h4;
    *(ushort4*)(alo + (size_t)n * F + fo) = l4;
}

// ==================== fused MLP: h2 = (relu(A@W1+b1))@W2 + b2, + BN stats ====================
// A: bf16 hi/lo planes [M][K]; W1t: [256][K] planes; W2t: [128][256] planes.
// hidden (128x256 bf16 hi/lo) lives entirely in LDS. 512 threads = 8 waves.
// Phase 1: wave (wm=wv>>2, wn=wv&3) computes 64x64 tile of hidden.
// Phase 2: K-split: wk=wv>>2 half of K=256; tile t2=wv&3 (wm2=t2>>1, wn2=t2&1);
//          wk=1 partial accs combined via LDS scratch (reuses dead hidden buffer).
// 3-term split everywhere: X*Y ~= Xh*Yh + Xh*Yl + Xl*Yh (fp32-level accuracy).
__global__ __launch_bounds__(512)
void fused_mlp_kernel(const unsigned short* __restrict__ Ahi, const unsigned short* __restrict__ Alo,
                      const unsigned short* __restrict__ W1hi, const unsigned short* __restrict__ W1lo,
                      const unsigned short* __restrict__ W2hi, const unsigned short* __restrict__ W2lo,
                      const float* __restrict__ b1, const float* __restrict__ b2,
                      float* __restrict__ Of, float* __restrict__ bnsums,
                      int M, int K)
{
    __shared__ __align__(16) unsigned short AsL[2][4][128][8];    // 16 KB A-tile staging
    __shared__ __align__(16) unsigned short hidL[2][32][128][8];  // 128 KB hidden planes
    __shared__ float sred[GHC], qred[GHC];                        // 1 KB BN partials

    const int tid = threadIdx.x;
    const int wv = tid >> 6, lane = tid & 63;
    const int r = lane & 15, g = lane >> 4;
    const int row0 = blockIdx.x * 128;

    if (tid < GHC) { sred[tid] = 0.f; qred[tid] = 0.f; }

    // ---------------- phase 1: hidden = relu(A @ W1 + b1) ----------------
    const int wm = wv >> 2, wn = wv & 3;
    f32x4 acc[4][4];
#pragma unroll
    for (int mi = 0; mi < 4; ++mi)
#pragma unroll
        for (int ni = 0; ni < 4; ++ni) acc[mi][ni] = 0.f;

    // staging map: cell c=tid -> row=c&127, kgroup=c>>7 ; LDS linear = c*16B
    const int srow = tid & 127, skg = tid >> 7;
    int arow = row0 + srow; if (arow >= M) arow = M - 1;
    unsigned short* dA0 = &AsL[0][0][0][0] + wv * 512;   // wave-uniform dest
    unsigned short* dA1 = &AsL[1][0][0][0] + wv * 512;

    for (int k0 = 0; k0 < K; k0 += 32) {
        const size_t aoff = (size_t)arow * K + k0 + skg * 8;
        load_lds16(Ahi + aoff, dA0);
        load_lds16(Alo + aoff, dA1);
        __syncthreads();
        bf16x8 ah[4], al[4], bh[4], bl[4];
#pragma unroll
        for (int i = 0; i < 4; ++i) {
            const int ar = wm * 64 + i * 16 + r;
            ah[i] = *(const bf16x8*)&AsL[0][g][ar][0];
            al[i] = *(const bf16x8*)&AsL[1][g][ar][0];
            const int n1 = wn * 64 + i * 16 + r;
            const size_t w1off = (size_t)n1 * K + k0 + g * 8;
            bh[i] = *(const bf16x8*)(W1hi + w1off);
            bl[i] = *(const bf16x8*)(W1lo + w1off);
        }
#pragma unroll
        for (int mi = 0; mi < 4; ++mi)
#pragma unroll
            for (int ni = 0; ni < 4; ++ni) {
                acc[mi][ni] = __builtin_amdgcn_mfma_f32_16x16x32_bf16(ah[mi], bh[ni], acc[mi][ni], 0, 0, 0);
                acc[mi][ni] = __builtin_amdgcn_mfma_f32_16x16x32_bf16(ah[mi], bl[ni], acc[mi][ni], 0, 0, 0);
                acc[mi][ni] = __builtin_amdgcn_mfma_f32_16x16x32_bf16(al[mi], bh[ni], acc[mi][ni], 0, 0, 0);
            }
        __syncthreads();
    }
    // epilogue: bias+relu, split, write into hidL (hidden col n1 = GEMM2 k-index)
#pragma unroll
    for (int ni = 0; ni < 4; ++ni) {
        const int n1 = wn * 64 + ni * 16 + r;
        const float bb = b1[n1];
#pragma unroll
        for (int mi = 0; mi < 4; ++mi)
#pragma unroll
            for (int reg = 0; reg < 4; ++reg) {
                const int lrow = wm * 64 + mi * 16 + g * 4 + reg;
                float v = fmaxf(acc[mi][ni][reg] + bb, 0.f);
                unsigned short h = f2bf(v);
                hidL[0][n1 >> 3][lrow][n1 & 7] = h;
                hidL[1][n1 >> 3][lrow][n1 & 7] = f2bf(v - bf2f(h));
            }
    }
    __syncthreads();

    // ---------------- phase 2: h2 = hidden @ W2 + b2 ----------------
    const int wk = wv >> 2, t2 = wv & 3, wm2 = t2 >> 1, wn2 = t2 & 1;
#pragma unroll
    for (int mi = 0; mi < 4; ++mi)
#pragma unroll
        for (int ni = 0; ni < 4; ++ni) acc[mi][ni] = 0.f;

    const int kb = wk * 128;
#pragma unroll
    for (int s = 0; s < 4; ++s) {
        const int k0 = kb + s * 32;
        bf16x8 a2h[4], a2l[4], b2h[4], b2l[4];
#pragma unroll
        for (int i = 0; i < 4; ++i) {
            const int ar = wm2 * 64 + i * 16 + r;
            a2h[i] = *(const bf16x8*)&hidL[0][(k0 >> 3) + g][ar][0];
            a2l[i] = *(const bf16x8*)&hidL[1][(k0 >> 3) + g][ar][0];
            const int n2 = wn2 * 64 + i * 16 + r;
            const size_t w2off = (size_t)n2 * 256 + k0 + g * 8;
            b2h[i] = *(const bf16x8*)(W2hi + w2off);
            b2l[i] = *(const bf16x8*)(W2lo + w2off);
        }
#pragma unroll
        for (int mi = 0; mi < 4; ++mi)
#pragma unroll
            for (int ni = 0; ni < 4; ++ni) {
                acc[mi][ni] = __builtin_amdgcn_mfma_f32_16x16x32_bf16(a2h[mi], b2h[ni], acc[mi][ni], 0, 0, 0);
                acc[mi][ni] = __builtin_amdgcn_mfma_f32_16x16x32_bf16(a2h[mi], b2l[ni], acc[mi][ni], 0, 0, 0);
                acc[mi][ni] = __builtin_amdgcn_mfma_f32_16x16x32_bf16(a2l[mi], b2h[ni], acc[mi][ni], 0, 0, 0);
            }
    }
    __syncthreads();

    // combine K-halves through LDS scratch (hidden buffer is dead now)
    float* scr = (float*)&hidL[0][0][0][0];   // 4 tiles x 64 cols x 68 floats = 69632 B
    if (wk == 1) {
#pragma unroll
        for (int mi = 0; mi < 4; ++mi)
#pragma unroll
            for (int ni = 0; ni < 4; ++ni)
                *(f32x4*)&scr[((t2 * 64 + ni * 16 + r) * 68 + mi * 16 + g * 4)] = acc[mi][ni];
    }
    __syncthreads();
    if (wk == 0) {
        float sl[4] = {0.f, 0.f, 0.f, 0.f}, ql[4] = {0.f, 0.f, 0.f, 0.f};
#pragma unroll
        for (int ni = 0; ni < 4; ++ni) {
            const int n2 = wn2 * 64 + ni * 16 + r;
            const float bb = b2[n2];
#pragma unroll
            for (int mi = 0; mi < 4; ++mi) {
                f32x4 p = *(const f32x4*)&scr[((t2 * 64 + ni * 16 + r) * 68 + mi * 16 + g * 4)];
#pragma unroll
                for (int reg = 0; reg < 4; ++reg) {
                    const int grow = row0 + wm2 * 64 + mi * 16 + g * 4 + reg;
                    if (grow < M) {
                        float v = acc[mi][ni][reg] + p[reg] + bb;
                        Of[(size_t)grow * GHC + n2] = v;
                        sl[ni] += v; ql[ni] += v * v;
                    }
                }
            }
        }
#pragma unroll
        for (int ni = 0; ni < 4; ++ni) {
            const int n2 = wn2 * 64 + ni * 16 + r;
            atomicAdd(&sred[n2], sl[ni]);
            atomicAdd(&qred[n2], ql[ni]);
        }
    }
    __syncthreads();
    if (tid < GHC) {
        atomicAdd(&bnsums[tid], sred[tid]);
        atomicAdd(&bnsums[GHC + tid], qred[tid]);
    }
}

// ==================== BN finalize / apply ====================
__global__ void bn_finalize_kernel(const float* __restrict__ sums,
    const float* __restrict__ gamma, const float* __restrict__ beta,
    float* __restrict__ ss) {
    int f = threadIdx.x;
    if (f < GHC) {
        float mu = sums[f] * (1.f / N_NODES);
        float var = sums[GHC + f] * (1.f / N_NODES) - mu * mu;
        float sc = gamma[f] * rsqrtf(var + BN_EPS);
        ss[f] = sc;
        ss[GHC + f] = beta[f] - mu * sc;
    }
}

__global__ __launch_bounds__(256)
void bn_apply_kernel(const float* __restrict__ h2, const float* __restrict__ ss,
                     float* __restrict__ hout) {
    int idx = blockIdx.x * blockDim.x + threadIdx.x;
    int node = idx >> 5;
    if (node >= N_NODES) return;
    int f = (idx & 31) * 4;
    float4 v = *(const float4*)(h2 + (size_t)node * GHC + f);
    float4 sc = *(const float4*)(ss + f);
    float4 sh = *(const float4*)(ss + GHC + f);
    float4 o;
    o.x = fmaxf(v.x * sc.x + sh.x, 0.f);
    o.y = fmaxf(v.y * sc.y + sh.y, 0.f);
    o.z = fmaxf(v.z * sc.z + sh.z, 0.f);
    o.w = fmaxf(v.w * sc.w + sh.w, 0.f);
    *(float4*)(hout + (size_t)node * GHC + f) = o;
}

// ==================== per-graph mean pool (batch sorted) ====================
__global__ __launch_bounds__(128)
void pool_kernel(const float* __restrict__ h, const int* __restrict__ gptr,
                 float* __restrict__ z, int loff) {
    int g = blockIdx.x;
    int f = threadIdx.x;
    int s = gptr[g], e = gptr[g + 1];
    float acc = 0.f;
    for (int i = s; i < e; ++i) acc += h[(size_t)i * GHC + f];
    z[(size_t)g * (N_LAYERS * GHC) + loff + f] = acc / fmaxf((float)(e - s), 1.f);
}

// ==================== fp32 GEMM 64x64 (head, tiny) ====================
template<bool RELU>
__global__ __launch_bounds__(256)
void gemm64_kernel(const float* __restrict__ A, const float* __restrict__ W,
                   const float* __restrict__ bias, float* __restrict__ C,
                   int M, int K, int N) {
    __shared__ float As[16][68];
    __shared__ float Bs[16][64];
    const int tid = threadIdx.x;
    const int row0 = blockIdx.x * 64;
    const int col0 = blockIdx.y * 64;
    const int tx = tid & 15;
    const int ty = tid >> 4;
    const int lm = tid >> 2;
    const int lk = (tid & 3) * 4;
    const int bkr = tid >> 4;
    const int bnc = (tid & 15) * 4;

    float acc[4][4];
#pragma unroll
    for (int i = 0; i < 4; ++i)
#pragma unroll
        for (int j = 0; j < 4; ++j) acc[i][j] = 0.f;

    const int arow = row0 + lm;
    for (int k0 = 0; k0 < K; k0 += 16) {
        if (arow < M) {
            float4 v = *(const float4*)(A + (size_t)arow * K + k0 + lk);
            As[lk + 0][lm] = v.x; As[lk + 1][lm] = v.y;
            As[lk + 2][lm] = v.z; As[lk + 3][lm] = v.w;
        } else {
#pragma unroll
            for (int j = 0; j < 4; ++j) As[lk + j][lm] = 0.f;
        }
        *(float4*)&Bs[bkr][bnc] = *(const float4*)(W + (size_t)(k0 + bkr) * N + col0 + bnc);
        __syncthreads();
#pragma unroll
        for (int kk = 0; kk < 16; ++kk) {
            float a[4], b[4];
            *(float4*)&a[0] = *(const float4*)&As[kk][ty * 4];
            *(float4*)&b[0] = *(const float4*)&Bs[kk][tx * 4];
#pragma unroll
            for (int i = 0; i < 4; ++i)
#pragma unroll
                for (int j = 0; j < 4; ++j)
                    acc[i][j] = fmaf(a[i], b[j], acc[i][j]);
        }
        __syncthreads();
    }
    float4 bv = *(const float4*)(bias + col0 + tx * 4);
    float bb[4] = {bv.x, bv.y, bv.z, bv.w};
#pragma unroll
    for (int i = 0; i < 4; ++i) {
        int row = row0 + ty * 4 + i;
        if (row < M) {
            float o[4];
#pragma unroll
            for (int j = 0; j < 4; ++j) {
                float t = acc[i][j] + bb[j];
                o[j] = RELU ? fmaxf(t, 0.f) : t;
            }
            *(float4*)(C + (size_t)row * N + col0 + tx * 4) = *(float4*)&o[0];
        }
    }
}

extern "C" void kernel_launch(void* const* d_in, const int* in_sizes, int n_in,
                              void* d_out, int out_size, void* d_ws, size_t ws_size,
                              hipStream_t stream)
{
    const float* x = (const float*)d_in[0];
    const int* edge = (const int*)d_in[1];
    const int* batch = (const int*)d_in[2];
    const float* W1_0 = (const float*)d_in[3];
    const float* b1_0 = (const float*)d_in[4];
    const float* W2_0 = (const float*)d_in[5];
    const float* b2_0 = (const float*)d_in[6];
    const float* W1s = (const float*)d_in[7];
    const float* b1s = (const float*)d_in[8];
    const float* W2s = (const float*)d_in[9];
    const float* b2s = (const float*)d_in[10];
    const float* gamma = (const float*)d_in[11];
    const float* beta = (const float*)d_in[12];
    const float* Wm1 = (const float*)d_in[13];
    const float* bm1 = (const float*)d_in[14];
    const float* Wm2 = (const float*)d_in[15];
    const float* bm2 = (const float*)d_in[16];
    const int* srcI = edge;
    const int* dstI = edge + N_EDGES;

    // ---- workspace layout (~165 MB) ----
    unsigned short* agg_hi = (unsigned short*)d_ws;              // N*128 bf16
    unsigned short* agg_lo = agg_hi + (size_t)N_NODES * GHC;     // N*128 bf16
    float* h2 = (float*)(agg_lo + (size_t)N_NODES * GHC);        // N*128 fp32
    float* hbuf = h2 + (size_t)N_NODES * GHC;                    // N*128 fp32
    float* z = hbuf + (size_t)N_NODES * GHC;                     // 1024*640
    float* zh = z + (size_t)N_GRAPHS * N_LAYERS * GHC;           // 1024*512
    float* bnsums = zh + (size_t)N_GRAPHS * NHID;                // 256
    float* bnss = bnsums + 2 * GHC;                              // 256
    unsigned short* w1t_hi = (unsigned short*)(bnss + 2 * GHC);  // 256*128
    unsigned short* w1t_lo = w1t_hi + 256 * GHC;
    unsigned short* w2t_hi = w1t_lo + 256 * GHC;                 // 128*256
    unsigned short* w2t_lo = w2t_hi + 256 * GHC;
    int* ideg = (int*)(w2t_lo + 256 * GHC);                      // N
    int* iptr = ideg + N_NODES;                                  // N+1
    int* iadj = iptr + N_NODES + 1;                              // E
    int* ibtot = iadj + N_EDGES;                                 // 128
    int* igptr = ibtot + 128;                                    // G+1

    // ---- CSR + graph ptr build ----
    hipMemsetAsync(ideg, 0, N_NODES * sizeof(int), stream);
    deg_kernel<<<(N_EDGES + 255) / 256, 256, 0, stream>>>(dstI, ideg);
    scan1_kernel<<<NCHUNKS, SCHUNK, 0, stream>>>(ideg, iptr, ibtot);
    scan2_kernel<<<1, 128, 0, stream>>>(ibtot);
    scan3_kernel<<<(N_NODES + 255) / 256, 256, 0, stream>>>(iptr, ibtot);
    hipMemcpyAsync(ideg, iptr, N_NODES * sizeof(int), hipMemcpyDeviceToDevice, stream);
    fill_kernel<<<(N_EDGES + 255) / 256, 256, 0, stream>>>(srcI, dstI, ideg, iadj);
    gptr_kernel<<<(N_GRAPHS + 1 + 255) / 256, 256, 0, stream>>>(batch, igptr);

    const int MB = (N_NODES + 127) / 128;   // 782
    const float* hin = x;
    for (int l = 0; l < N_LAYERS; ++l) {
        const int F = (l == 0) ? F_IN : GHC;
        const float* W1 = (l == 0) ? W1_0 : W1s + (size_t)(l - 1) * GHC * 2 * GHC;
        const float* b1 = (l == 0) ? b1_0 : b1s + (size_t)(l - 1) * 2 * GHC;
        const float* W2 = (l == 0) ? W2_0 : W2s + (size_t)(l - 1) * 2 * GHC * GHC;
        const float* b2 = (l == 0) ? b2_0 : b2s + (size_t)(l - 1) * GHC;

        wconv_kernel<<<(F * 2 * GHC + 255) / 256, 256, 0, stream>>>(W1, w1t_hi, w1t_lo, F, 2 * GHC);
        wconv_kernel<<<(2 * GHC * GHC + 255) / 256, 256, 0, stream>>>(W2, w2t_hi, w2t_lo, 2 * GHC, GHC);

        if (l == 0)
            gather_agg_kernel<F_IN><<<(N_NODES + 31) / 32, 256, 0, stream>>>(hin, iptr, iadj, agg_hi, agg_lo);
        else
            gather_agg_kernel<GHC><<<(N_NODES + 7) / 8, 256, 0, stream>>>(hin, iptr, iadj, agg_hi, agg_lo);

        hipMemsetAsync(bnsums, 0, sizeof(float) * 2 * GHC, stream);
        fused_mlp_kernel<<<MB, 512, 0, stream>>>(agg_hi, agg_lo, w1t_hi, w1t_lo, w2t_hi, w2t_lo,
                                                 b1, b2, h2, bnsums, N_NODES, F);

        bn_finalize_kernel<<<1, GHC, 0, stream>>>(bnsums, gamma + l * GHC, beta + l * GHC, bnss);
        bn_apply_kernel<<<(N_NODES * 32 + 255) / 256, 256, 0, stream>>>(h2, bnss, hbuf);
        pool_kernel<<<N_GRAPHS, 128, 0, stream>>>(hbuf, igptr, z, l * GHC);

        hin = hbuf;
    }

    dim3 gh1(N_GRAPHS / 64, NHID / 64);
    gemm64_kernel<true><<<gh1, 256, 0, stream>>>(z, Wm1, bm1, zh, N_GRAPHS, N_LAYERS * GHC, NHID);
    dim3 gh2(N_GRAPHS / 64, NOUT / 64);
    gemm64_kernel<false><<<gh2, 256, 0, stream>>>(zh, Wm2, bm2, (float*)d_out, N_GRAPHS, NHID, NOUT);
}

// Round 8
// 1342.339 us; speedup vs baseline: 5.2586x; 1.0994x over previous
//
#include <hip/hip_runtime.h>

#define N_NODES 100000
#define N_EDGES 600000
#define N_GRAPHS 1024
#define F_IN 32
#define GHC 128
#define NHID 512
#define NOUT 256
#define N_LAYERS 5
#define BN_EPS 1e-5f

typedef __attribute__((ext_vector_type(4))) float f32x4;
typedef __attribute__((ext_vector_type(8))) short bf16x8;

__device__ __forceinline__ unsigned short f2bf(float f) {
    unsigned int u = __float_as_uint(f);
    u = u + 0x7fffu + ((u >> 16) & 1u);
    return (unsigned short)(u >> 16);
}
__device__ __forceinline__ float bf2f(unsigned short h) {
    return __uint_as_float(((unsigned int)h) << 16);
}

// ==================== CSR build ====================
__global__ void deg_kernel(const int* __restrict__ dst, int* __restrict__ deg) {
    int e = blockIdx.x * blockDim.x + threadIdx.x;
    if (e < N_EDGES) atomicAdd(&deg[dst[e]], 1);
}

#define SCHUNK 1024
#define NCHUNKS ((N_NODES + SCHUNK - 1) / SCHUNK)   // 98

__global__ __launch_bounds__(1024)
void scan1_kernel(const int* __restrict__ deg, int* __restrict__ ptr, int* __restrict__ btot) {
    __shared__ int buf[SCHUNK];
    int t = threadIdx.x;
    int i = blockIdx.x * SCHUNK + t;
    int v = (i < N_NODES) ? deg[i] : 0;
    buf[t] = v;
    __syncthreads();
    for (int off = 1; off < SCHUNK; off <<= 1) {
        int u = (t >= off) ? buf[t - off] : 0;
        __syncthreads();
        buf[t] += u;
        __syncthreads();
    }
    if (i < N_NODES) ptr[i + 1] = buf[t];
    if (t == SCHUNK - 1) btot[blockIdx.x] = buf[t];
}

__global__ __launch_bounds__(128)
void scan2_kernel(int* __restrict__ btot) {
    __shared__ int buf[128];
    int t = threadIdx.x;
    int v = (t < NCHUNKS) ? btot[t] : 0;
    buf[t] = v;
    __syncthreads();
    for (int off = 1; off < 128; off <<= 1) {
        int u = (t >= off) ? buf[t - off] : 0;
        __syncthreads();
        buf[t] += u;
        __syncthreads();
    }
    if (t < NCHUNKS) btot[t] = buf[t] - v;
}

__global__ void scan3_kernel(int* __restrict__ ptr, const int* __restrict__ btot) {
    int i = blockIdx.x * blockDim.x + threadIdx.x;
    if (i < N_NODES) ptr[i + 1] += btot[i >> 10];
    if (i == 0) ptr[0] = 0;
}

__global__ void fill_kernel(const int* __restrict__ src, const int* __restrict__ dst,
                            int* __restrict__ cur, int* __restrict__ adj) {
    int e = blockIdx.x * blockDim.x + threadIdx.x;
    if (e >= N_EDGES) return;
    int p = atomicAdd(&cur[dst[e]], 1);
    adj[p] = src[e];
}

__global__ void gptr_kernel(const int* __restrict__ batch, int* __restrict__ gptr) {
    int g = blockIdx.x * blockDim.x + threadIdx.x;
    if (g > N_GRAPHS) return;
    int lo = 0, hi = N_NODES;
    while (lo < hi) { int mid = (lo + hi) >> 1; if (batch[mid] < g) lo = mid + 1; else hi = mid; }
    gptr[g] = lo;
}

// ==================== weight transpose + bf16 split: W[K][N] -> Wt_hi/lo [N][K] ====================
__global__ void wconv_kernel(const float* __restrict__ W, unsigned short* __restrict__ thi,
                             unsigned short* __restrict__ tlo, int K, int N) {
    int i = blockIdx.x * blockDim.x + threadIdx.x;
    if (i >= K * N) return;
    int k = i / N, n = i - k * N;
    float v = W[i];
    unsigned short h = f2bf(v);
    thi[(size_t)n * K + k] = h;
    tlo[(size_t)n * K + k] = f2bf(v - bf2f(h));
}

// ==================== gather aggregation (+ inline BN of previous layer) -> bf16 planes ====================
// BN=true: input is raw h2 of previous layer; apply val = relu(v*sc+sh) elementwise on the fly.
template<int F, bool BN>
__global__ __launch_bounds__(256)
void gather_agg_kernel(const float* __restrict__ x, const int* __restrict__ ptr,
                       const int* __restrict__ adj, const float* __restrict__ ss,
                       unsigned short* __restrict__ ahi, unsigned short* __restrict__ alo) {
    constexpr int F4 = F / 4;
    constexpr int NPB = 256 / F4;
    int f4 = threadIdx.x % F4;
    int n = blockIdx.x * NPB + threadIdx.x / F4;
    if (n >= N_NODES) return;
    const int fo = f4 * 4;
    float4 sc, sh;
    if (BN) { sc = *(const float4*)(ss + fo); sh = *(const float4*)(ss + GHC + fo); }
    float4 acc = *(const float4*)(x + (size_t)n * F + fo);
    if (BN) {
        acc.x = fmaxf(acc.x * sc.x + sh.x, 0.f); acc.y = fmaxf(acc.y * sc.y + sh.y, 0.f);
        acc.z = fmaxf(acc.z * sc.z + sh.z, 0.f); acc.w = fmaxf(acc.w * sc.w + sh.w, 0.f);
    }
    int p1 = ptr[n + 1];
    for (int p = ptr[n]; p < p1; ++p) {
        int s = adj[p];
        float4 v = *(const float4*)(x + (size_t)s * F + fo);
        if (BN) {
            v.x = fmaxf(v.x * sc.x + sh.x, 0.f); v.y = fmaxf(v.y * sc.y + sh.y, 0.f);
            v.z = fmaxf(v.z * sc.z + sh.z, 0.f); v.w = fmaxf(v.w * sc.w + sh.w, 0.f);
        }
        acc.x += v.x; acc.y += v.y; acc.z += v.z; acc.w += v.w;
    }
    ushort4 h4, l4;
    h4.x = f2bf(acc.x); l4.x = f2bf(acc.x - bf2f(h4.x));
    h4.y = f2bf(acc.y); l4.y = f2bf(acc.y - bf2f(h4.y));
    h4.z = f2bf(acc.z); l4.z = f2bf(acc.z - bf2f(h4.z));
    h4.w = f2bf(acc.w); l4.w = f2bf(acc.w - bf2f(h4.w));
    *(ushort4*)(ahi + (size_t)n * F + fo) = h4;
    *(ushort4*)(alo + (size_t)n * F + fo) = l4;
}

// ==================== fused MLP v2: h2 = (relu(A@W1+b1))@W2 + b2, + BN stats ====================
// 256 threads = 4 waves (2x2 grid of 64x64 tiles). hidden processed in TWO 128-col halves:
//   phase1(hh): acc1 = A @ W1[:, hh*128..] (A and W1 fragments loaded DIRECT from global)
//   -> relu+split -> hidL (64 KB)  -> phase2: acc2 += hidL @ W2[hh*128.., :]
// acc2 persists in registers across halves; no K-split, no LDS scratch, 8 barriers total.
// 3-term split: X*Y ~= Xh*Yh + Xh*Yl + Xl*Yh (fp32-level accuracy).
__global__ __launch_bounds__(256, 2)
void fused_mlp_kernel(const unsigned short* __restrict__ Ahi, const unsigned short* __restrict__ Alo,
                      const unsigned short* __restrict__ W1hi, const unsigned short* __restrict__ W1lo,
                      const unsigned short* __restrict__ W2hi, const unsigned short* __restrict__ W2lo,
                      const float* __restrict__ b1, const float* __restrict__ b2,
                      float* __restrict__ Of, float* __restrict__ bnsums,
                      int M, int K)
{
    __shared__ __align__(16) unsigned short hidL[2][16][128][8];  // 64 KB hidden half planes
    __shared__ float sred[GHC], qred[GHC];

    const int tid = threadIdx.x;
    const int wv = tid >> 6, lane = tid & 63;
    const int r = lane & 15, g = lane >> 4;
    const int wm = wv >> 1, wn = wv & 1;
    const int row0 = blockIdx.x * 128;

    if (tid < GHC) { sred[tid] = 0.f; qred[tid] = 0.f; }

    int arows[4];
#pragma unroll
    for (int i = 0; i < 4; ++i) {
        int rr = row0 + wm * 64 + i * 16 + r;
        arows[i] = rr < M ? rr : M - 1;
    }

    f32x4 acc2[4][4];
#pragma unroll
    for (int mi = 0; mi < 4; ++mi)
#pragma unroll
        for (int ni = 0; ni < 4; ++ni) acc2[mi][ni] = 0.f;

#pragma unroll
    for (int hh = 0; hh < 2; ++hh) {
        // ---------- phase 1: hidden half = A @ W1[:, hh*128 + 0..127] ----------
        f32x4 acc1[4][4];
#pragma unroll
        for (int mi = 0; mi < 4; ++mi)
#pragma unroll
            for (int ni = 0; ni < 4; ++ni) acc1[mi][ni] = 0.f;

        for (int k0 = 0; k0 < K; k0 += 32) {
            bf16x8 ah[4], al[4], bh[4], bl[4];
#pragma unroll
            for (int i = 0; i < 4; ++i) {
                const size_t ao = (size_t)arows[i] * K + k0 + g * 8;
                ah[i] = *(const bf16x8*)(Ahi + ao);
                al[i] = *(const bf16x8*)(Alo + ao);
                const int n1g = hh * 128 + wn * 64 + i * 16 + r;
                const size_t wo = (size_t)n1g * K + k0 + g * 8;
                bh[i] = *(const bf16x8*)(W1hi + wo);
                bl[i] = *(const bf16x8*)(W1lo + wo);
            }
#pragma unroll
            for (int mi = 0; mi < 4; ++mi)
#pragma unroll
                for (int ni = 0; ni < 4; ++ni) {
                    acc1[mi][ni] = __builtin_amdgcn_mfma_f32_16x16x32_bf16(ah[mi], bh[ni], acc1[mi][ni], 0, 0, 0);
                    acc1[mi][ni] = __builtin_amdgcn_mfma_f32_16x16x32_bf16(ah[mi], bl[ni], acc1[mi][ni], 0, 0, 0);
                    acc1[mi][ni] = __builtin_amdgcn_mfma_f32_16x16x32_bf16(al[mi], bh[ni], acc1[mi][ni], 0, 0, 0);
                }
        }
        __syncthreads();   // previous half's phase-2 readers are done with hidL
        // relu + bias + split -> hidL
#pragma unroll
        for (int ni = 0; ni < 4; ++ni) {
            const int n1 = wn * 64 + ni * 16 + r;
            const float bb = b1[hh * 128 + n1];
#pragma unroll
            for (int mi = 0; mi < 4; ++mi)
#pragma unroll
                for (int reg = 0; reg < 4; ++reg) {
                    const int lrow = wm * 64 + mi * 16 + g * 4 + reg;
                    float v = fmaxf(acc1[mi][ni][reg] + bb, 0.f);
                    unsigned short h = f2bf(v);
                    hidL[0][n1 >> 3][lrow][n1 & 7] = h;
                    hidL[1][n1 >> 3][lrow][n1 & 7] = f2bf(v - bf2f(h));
                }
        }
        __syncthreads();
        // ---------- phase 2: acc2 += hidden_half @ W2[hh*128.., :] ----------
#pragma unroll
        for (int s = 0; s < 4; ++s) {
            bf16x8 a2h[4], a2l[4], b2h[4], b2l[4];
#pragma unroll
            for (int i = 0; i < 4; ++i) {
                const int ar = wm * 64 + i * 16 + r;
                a2h[i] = *(const bf16x8*)&hidL[0][s * 4 + g][ar][0];
                a2l[i] = *(const bf16x8*)&hidL[1][s * 4 + g][ar][0];
                const int n2 = wn * 64 + i * 16 + r;
                const size_t wo2 = (size_t)n2 * 256 + hh * 128 + s * 32 + g * 8;
                b2h[i] = *(const bf16x8*)(W2hi + wo2);
                b2l[i] = *(const bf16x8*)(W2lo + wo2);
            }
#pragma unroll
            for (int mi = 0; mi < 4; ++mi)
#pragma unroll
                for (int ni = 0; ni < 4; ++ni) {
                    acc2[mi][ni] = __builtin_amdgcn_mfma_f32_16x16x32_bf16(a2h[mi], b2h[ni], acc2[mi][ni], 0, 0, 0);
                    acc2[mi][ni] = __builtin_amdgcn_mfma_f32_16x16x32_bf16(a2h[mi], b2l[ni], acc2[mi][ni], 0, 0, 0);
                    acc2[mi][ni] = __builtin_amdgcn_mfma_f32_16x16x32_bf16(a2l[mi], b2h[ni], acc2[mi][ni], 0, 0, 0);
                }
        }
    }

    // ---------- epilogue: bias, write h2, BN partial sums ----------
    float sl[4] = {0.f, 0.f, 0.f, 0.f}, ql[4] = {0.f, 0.f, 0.f, 0.f};
#pragma unroll
    for (int ni = 0; ni < 4; ++ni) {
        const int n2 = wn * 64 + ni * 16 + r;
        const float bb = b2[n2];
#pragma unroll
        for (int mi = 0; mi < 4; ++mi)
#pragma unroll
            for (int reg = 0; reg < 4; ++reg) {
                const int grow = row0 + wm * 64 + mi * 16 + g * 4 + reg;
                if (grow < M) {
                    float v = acc2[mi][ni][reg] + bb;
                    Of[(size_t)grow * GHC + n2] = v;
                    sl[ni] += v; ql[ni] += v * v;
                }
            }
    }
#pragma unroll
    for (int ni = 0; ni < 4; ++ni) {
        const int n2 = wn * 64 + ni * 16 + r;
        atomicAdd(&sred[n2], sl[ni]);
        atomicAdd(&qred[n2], ql[ni]);
    }
    __syncthreads();
    if (tid < GHC) {
        atomicAdd(&bnsums[tid], sred[tid]);
        atomicAdd(&bnsums[GHC + tid], qred[tid]);
    }
}

// ==================== BN finalize ====================
__global__ void bn_finalize_kernel(const float* __restrict__ sums,
    const float* __restrict__ gamma, const float* __restrict__ beta,
    float* __restrict__ ss) {
    int f = threadIdx.x;
    if (f < GHC) {
        float mu = sums[f] * (1.f / N_NODES);
        float var = sums[GHC + f] * (1.f / N_NODES) - mu * mu;
        float sc = gamma[f] * rsqrtf(var + BN_EPS);
        ss[f] = sc;
        ss[GHC + f] = beta[f] - mu * sc;
    }
}

// ==================== per-graph mean pool with inline BN (batch sorted) ====================
__global__ __launch_bounds__(128)
void pool_kernel(const float* __restrict__ h2, const float* __restrict__ ss,
                 const int* __restrict__ gptr, float* __restrict__ z, int loff) {
    int g = blockIdx.x;
    int f = threadIdx.x;
    float sc = ss[f], sh = ss[GHC + f];
    int s = gptr[g], e = gptr[g + 1];
    float acc = 0.f;
    for (int i = s; i < e; ++i) acc += fmaxf(h2[(size_t)i * GHC + f] * sc + sh, 0.f);
    z[(size_t)g * (N_LAYERS * GHC) + loff + f] = acc / fmaxf((float)(e - s), 1.f);
}

// ==================== fp32 GEMM 64x64 (head, tiny) ====================
template<bool RELU>
__global__ __launch_bounds__(256)
void gemm64_kernel(const float* __restrict__ A, const float* __restrict__ W,
                   const float* __restrict__ bias, float* __restrict__ C,
                   int M, int K, int N) {
    __shared__ float As[16][68];
    __shared__ float Bs[16][64];
    const int tid = threadIdx.x;
    const int row0 = blockIdx.x * 64;
    const int col0 = blockIdx.y * 64;
    const int tx = tid & 15;
    const int ty = tid >> 4;
    const int lm = tid >> 2;
    const int lk = (tid & 3) * 4;
    const int bkr = tid >> 4;
    const int bnc = (tid & 15) * 4;

    float acc[4][4];
#pragma unroll
    for (int i = 0; i < 4; ++i)
#pragma unroll
        for (int j = 0; j < 4; ++j) acc[i][j] = 0.f;

    const int arow = row0 + lm;
    for (int k0 = 0; k0 < K; k0 += 16) {
        if (arow < M) {
            float4 v = *(const float4*)(A + (size_t)arow * K + k0 + lk);
            As[lk + 0][lm] = v.x; As[lk + 1][lm] = v.y;
            As[lk + 2][lm] = v.z; As[lk + 3][lm] = v.w;
        } else {
#pragma unroll
            for (int j = 0; j < 4; ++j) As[lk + j][lm] = 0.f;
        }
        *(float4*)&Bs[bkr][bnc] = *(const float4*)(W + (size_t)(k0 + bkr) * N + col0 + bnc);
        __syncthreads();
#pragma unroll
        for (int kk = 0; kk < 16; ++kk) {
            float a[4], b[4];
            *(float4*)&a[0] = *(const float4*)&As[kk][ty * 4];
            *(float4*)&b[0] = *(const float4*)&Bs[kk][tx * 4];
#pragma unroll
            for (int i = 0; i < 4; ++i)
#pragma unroll
                for (int j = 0; j < 4; ++j)
                    acc[i][j] = fmaf(a[i], b[j], acc[i][j]);
        }
        __syncthreads();
    }
    float4 bv = *(const float4*)(bias + col0 + tx * 4);
    float bb[4] = {bv.x, bv.y, bv.z, bv.w};
#pragma unroll
    for (int i = 0; i < 4; ++i) {
        int row = row0 + ty * 4 + i;
        if (row < M) {
            float o[4];
#pragma unroll
            for (int j = 0; j < 4; ++j) {
                float t = acc[i][j] + bb[j];
                o[j] = RELU ? fmaxf(t, 0.f) : t;
            }
            *(float4*)(C + (size_t)row * N + col0 + tx * 4) = *(float4*)&o[0];
        }
    }
}

extern "C" void kernel_launch(void* const* d_in, const int* in_sizes, int n_in,
                              void* d_out, int out_size, void* d_ws, size_t ws_size,
                              hipStream_t stream)
{
    const float* x = (const float*)d_in[0];
    const int* edge = (const int*)d_in[1];
    const int* batch = (const int*)d_in[2];
    const float* W1_0 = (const float*)d_in[3];
    const float* b1_0 = (const float*)d_in[4];
    const float* W2_0 = (const float*)d_in[5];
    const float* b2_0 = (const float*)d_in[6];
    const float* W1s = (const float*)d_in[7];
    const float* b1s = (const float*)d_in[8];
    const float* W2s = (const float*)d_in[9];
    const float* b2s = (const float*)d_in[10];
    const float* gamma = (const float*)d_in[11];
    const float* beta = (const float*)d_in[12];
    const float* Wm1 = (const float*)d_in[13];
    const float* bm1 = (const float*)d_in[14];
    const float* Wm2 = (const float*)d_in[15];
    const float* bm2 = (const float*)d_in[16];
    const int* srcI = edge;
    const int* dstI = edge + N_EDGES;

    // ---- workspace layout (~115 MB) ----
    unsigned short* agg_hi = (unsigned short*)d_ws;              // N*128 bf16
    unsigned short* agg_lo = agg_hi + (size_t)N_NODES * GHC;     // N*128 bf16
    float* h2 = (float*)(agg_lo + (size_t)N_NODES * GHC);        // N*128 fp32
    float* z = h2 + (size_t)N_NODES * GHC;                       // 1024*640
    float* zh = z + (size_t)N_GRAPHS * N_LAYERS * GHC;           // 1024*512
    float* bnsums = zh + (size_t)N_GRAPHS * NHID;                // 256
    float* bnss = bnsums + 2 * GHC;                              // 256
    unsigned short* w1t_hi = (unsigned short*)(bnss + 2 * GHC);  // 256*128
    unsigned short* w1t_lo = w1t_hi + 256 * GHC;
    unsigned short* w2t_hi = w1t_lo + 256 * GHC;                 // 128*256
    unsigned short* w2t_lo = w2t_hi + 256 * GHC;
    int* ideg = (int*)(w2t_lo + 256 * GHC);                      // N
    int* iptr = ideg + N_NODES;                                  // N+1
    int* iadj = iptr + N_NODES + 1;                              // E
    int* ibtot = iadj + N_EDGES;                                 // 128
    int* igptr = ibtot + 128;                                    // G+1

    // ---- CSR + graph ptr build ----
    hipMemsetAsync(ideg, 0, N_NODES * sizeof(int), stream);
    deg_kernel<<<(N_EDGES + 255) / 256, 256, 0, stream>>>(dstI, ideg);
    scan1_kernel<<<NCHUNKS, SCHUNK, 0, stream>>>(ideg, iptr, ibtot);
    scan2_kernel<<<1, 128, 0, stream>>>(ibtot);
    scan3_kernel<<<(N_NODES + 255) / 256, 256, 0, stream>>>(iptr, ibtot);
    hipMemcpyAsync(ideg, iptr, N_NODES * sizeof(int), hipMemcpyDeviceToDevice, stream);
    fill_kernel<<<(N_EDGES + 255) / 256, 256, 0, stream>>>(srcI, dstI, ideg, iadj);
    gptr_kernel<<<(N_GRAPHS + 1 + 255) / 256, 256, 0, stream>>>(batch, igptr);

    const int MB = (N_NODES + 127) / 128;   // 782
    for (int l = 0; l < N_LAYERS; ++l) {
        const int F = (l == 0) ? F_IN : GHC;
        const float* W1 = (l == 0) ? W1_0 : W1s + (size_t)(l - 1) * GHC * 2 * GHC;
        const float* b1 = (l == 0) ? b1_0 : b1s + (size_t)(l - 1) * 2 * GHC;
        const float* W2 = (l == 0) ? W2_0 : W2s + (size_t)(l - 1) * 2 * GHC * GHC;
        const float* b2 = (l == 0) ? b2_0 : b2s + (size_t)(l - 1) * GHC;

        wconv_kernel<<<(F * 2 * GHC + 255) / 256, 256, 0, stream>>>(W1, w1t_hi, w1t_lo, F, 2 * GHC);
        wconv_kernel<<<(2 * GHC * GHC + 255) / 256, 256, 0, stream>>>(W2, w2t_hi, w2t_lo, 2 * GHC, GHC);

        if (l == 0)
            gather_agg_kernel<F_IN, false><<<(N_NODES + 31) / 32, 256, 0, stream>>>(x, iptr, iadj, nullptr, agg_hi, agg_lo);
        else
            gather_agg_kernel<GHC, true><<<(N_NODES + 7) / 8, 256, 0, stream>>>(h2, iptr, iadj, bnss, agg_hi, agg_lo);

        hipMemsetAsync(bnsums, 0, sizeof(float) * 2 * GHC, stream);
        fused_mlp_kernel<<<MB, 256, 0, stream>>>(agg_hi, agg_lo, w1t_hi, w1t_lo, w2t_hi, w2t_lo,
                                                 b1, b2, h2, bnsums, N_NODES, F);

        bn_finalize_kernel<<<1, GHC, 0, stream>>>(bnsums, gamma + l * GHC, beta + l * GHC, bnss);
        pool_kernel<<<N_GRAPHS, 128, 0, stream>>>(h2, bnss, igptr, z, l * GHC);
    }

    dim3 gh1(N_GRAPHS / 64, NHID / 64);
    gemm64_kernel<true><<<gh1, 256, 0, stream>>>(z, Wm1, bm1, zh, N_GRAPHS, N_LAYERS * GHC, NHID);
    dim3 gh2(N_GRAPHS / 64, NOUT / 64);
    gemm64_kernel<false><<<gh2, 256, 0, stream>>>(zh, Wm2, bm2, (float*)d_out, N_GRAPHS, NHID, NOUT);
}